// Round 12
// baseline (196.577 us; speedup 1.0000x reference)
//
#include <hip/hip_runtime.h>

#define T_TOT 2304
#define S_LEN 128
#define D_IN  1024
#define D_H   64
#define BATCH 2
#define NROW  (BATCH * T_TOT)
#define CH    (T_TOT / 256)   // 9
#define SCALE 0.125f
#define KCHUNKS 8
#define KCW   (D_IN / KCHUNKS)   // 128
#define TB    16                 // t-rows per flash block
#define FCH   288                // s-chunk width (flash + pv split)
#define NSC   8                  // number of s-chunks
#define NTBLK (T_TOT / TB)       // 144
#define NT16  (T_TOT / 16)       // 144 col-tiles
#define NPART (NSC * 4)          // 32 partials per t-block

typedef unsigned short u16;
typedef __attribute__((ext_vector_type(8))) short short8;
typedef __attribute__((ext_vector_type(4))) float f32x4;
typedef __attribute__((ext_vector_type(4))) unsigned short u16x4;

static __device__ __forceinline__ u16 f2bf(float f) {
    unsigned u = __float_as_uint(f);
    unsigned r = (u + 0x7fffu + ((u >> 16) & 1u)) >> 16;
    return (u16)r;
}
static __device__ __forceinline__ float bf2f(u16 s) {
    return __uint_as_float((unsigned)s << 16);
}

// ---------------------------------------------------------------------------
// Kernel 1a: LayerNorm(x_row) -> xn hi/lo (split bf16). One block (256)/row.
// ---------------------------------------------------------------------------
__global__ __launch_bounds__(256) void k_ln(
    const float* __restrict__ x,
    const float* __restrict__ ln_g,  const float* __restrict__ ln_b,
    const float* __restrict__ ln_gs, const float* __restrict__ ln_bs,
    const float* __restrict__ ln_ge, const float* __restrict__ ln_be,
    u16* __restrict__ xn_hi, u16* __restrict__ xn_lo)
{
    __shared__ float red1[256], red2[256];
    const int row = blockIdx.x;
    const int t = row % T_TOT;
    const int tid = threadIdx.x;

    const float *gg, *bb;
    if (t < S_LEN)               { gg = ln_gs; bb = ln_bs; }
    else if (t >= T_TOT - S_LEN) { gg = ln_ge; bb = ln_be; }
    else                         { gg = ln_g;  bb = ln_b;  }

    const float4 xv = *(const float4*)(x + (size_t)row * D_IN + 4 * tid);
    float s  = xv.x + xv.y + xv.z + xv.w;
    float s2 = xv.x * xv.x + xv.y * xv.y + xv.z * xv.z + xv.w * xv.w;
    red1[tid] = s; red2[tid] = s2; __syncthreads();
    for (int off = 128; off > 0; off >>= 1) {
        if (tid < off) { red1[tid] += red1[tid + off]; red2[tid] += red2[tid + off]; }
        __syncthreads();
    }
    const float mean = red1[0] * (1.f / D_IN);
    const float var  = red2[0] * (1.f / D_IN) - mean * mean;
    const float rstd = rsqrtf(var + 1e-5f);

    const float4 gv = *(const float4*)(gg + 4 * tid);
    const float4 bv = *(const float4*)(bb + 4 * tid);
    float o0 = (xv.x - mean) * rstd * gv.x + bv.x;
    float o1 = (xv.y - mean) * rstd * gv.y + bv.y;
    float o2 = (xv.z - mean) * rstd * gv.z + bv.z;
    float o3 = (xv.w - mean) * rstd * gv.w + bv.w;

    u16x4 hv, lv;
    hv[0] = f2bf(o0); lv[0] = f2bf(o0 - bf2f(hv[0]));
    hv[1] = f2bf(o1); lv[1] = f2bf(o1 - bf2f(hv[1]));
    hv[2] = f2bf(o2); lv[2] = f2bf(o2 - bf2f(hv[2]));
    hv[3] = f2bf(o3); lv[3] = f2bf(o3 - bf2f(hv[3]));
    *(u16x4*)(xn_hi + (size_t)row * D_IN + 4 * tid) = hv;
    *(u16x4*)(xn_lo + (size_t)row * D_IN + 4 * tid) = lv;
}

// ---------------------------------------------------------------------------
// Kernel 1b: prep — transpose+split Wh/Whs/Whe, and split cope_emb^T
// ---------------------------------------------------------------------------
#define WPREP_N (3 * D_H * D_IN)
__global__ __launch_bounds__(256) void k_prep(
    const float* __restrict__ Wh, const float* __restrict__ Whs, const float* __restrict__ Whe,
    const float* __restrict__ cope,
    u16* __restrict__ wT_hi, u16* __restrict__ wT_lo,
    u16* __restrict__ cT_hi, u16* __restrict__ cT_lo)
{
    const int gid = blockIdx.x * 256 + threadIdx.x;
    if (gid < WPREP_N) {
        const int seg = gid >> 16;
        const int o = gid & 65535;
        const int j = o >> 10, k = o & 1023;
        const float* W = seg == 0 ? Wh : (seg == 1 ? Whs : Whe);
        const float f = W[k * D_H + j];
        const u16 hi = f2bf(f);
        wT_hi[gid] = hi;
        wT_lo[gid] = f2bf(f - bf2f(hi));
    } else {
        const int idx = gid - WPREP_N;
        if (idx < T_TOT * D_H) {
            const int n = idx >> 6, d = idx & 63;
            const float f = cope[(size_t)d * T_TOT + n];
            const u16 hi = f2bf(f);
            cT_hi[idx] = hi;
            cT_lo[idx] = f2bf(f - bf2f(hi));
        }
    }
}

// ---------------------------------------------------------------------------
// Kernel 1c: h_part[kc] = LN(x)[:, kc*128:+128] @ W_seg[kc chunk]  (MFMA, split)
// ---------------------------------------------------------------------------
__global__ __launch_bounds__(256) void k_hgemm(
    const u16* __restrict__ xn_hi, const u16* __restrict__ xn_lo,
    const u16* __restrict__ wT_hi, const u16* __restrict__ wT_lo,
    float* __restrict__ h_part)
{
    const int tile = blockIdx.x;              // 0..71
    const int kc   = blockIdx.y;              // 0..7
    const int k0   = kc * KCW;
    const int tt = tile % 36;
    const int seg = tt < 2 ? 1 : (tt >= 34 ? 2 : 0);

    __shared__ u16 Bh[64 * KCW];
    __shared__ u16 Bl[64 * KCW];

    const int tid = threadIdx.x;
    {
        const int r = tid >> 2;
        const int c0 = (tid & 3) * 32;
        const u16* sh = wT_hi + ((size_t)seg * D_H + r) * D_IN + k0 + c0;
        const u16* sl = wT_lo + ((size_t)seg * D_H + r) * D_IN + k0 + c0;
        const int sw = (r & 7) << 3;
        #pragma unroll
        for (int u = 0; u < 4; ++u) {
            const int col = c0 + 8 * u;
            *(short8*)&Bh[r * KCW + (col ^ sw)] = *(const short8*)(sh + 8 * u);
            *(short8*)&Bl[r * KCW + (col ^ sw)] = *(const short8*)(sl + 8 * u);
        }
    }
    __syncthreads();

    const int w = tid >> 6;
    const int lane = tid & 63;
    const int l15 = lane & 15, lg4 = lane >> 4;
    const int row0 = tile * 64 + w * 16;

    const size_t abase = (size_t)(row0 + l15) * D_IN + k0 + 8 * lg4;
    f32x4 acc[4] = {};

    #pragma unroll
    for (int kk = 0; kk < KCW / 32; ++kk) {
        short8 ah = *(const short8*)(xn_hi + abase + kk * 32);
        short8 al = *(const short8*)(xn_lo + abase + kk * 32);
        #pragma unroll
        for (int j = 0; j < 4; ++j) {
            const int brow = j * 16 + l15;
            const int col = (kk * 32 + 8 * lg4) ^ ((brow & 7) << 3);
            short8 bh = *(const short8*)&Bh[brow * KCW + col];
            short8 bl = *(const short8*)&Bl[brow * KCW + col];
            acc[j] = __builtin_amdgcn_mfma_f32_16x16x32_bf16(al, bh, acc[j], 0, 0, 0);
            acc[j] = __builtin_amdgcn_mfma_f32_16x16x32_bf16(ah, bl, acc[j], 0, 0, 0);
            acc[j] = __builtin_amdgcn_mfma_f32_16x16x32_bf16(ah, bh, acc[j], 0, 0, 0);
        }
    }
    float* hp = h_part + (size_t)kc * ((size_t)NROW * D_H);
    #pragma unroll
    for (int j = 0; j < 4; ++j)
        #pragma unroll
        for (int r = 0; r < 4; ++r)
            hp[(size_t)(row0 + 4 * lg4 + r) * D_H + j * 16 + l15] = acc[j][r];
}

// ---------------------------------------------------------------------------
// Kernel 1d: h = sum_kc h_part[kc]
// ---------------------------------------------------------------------------
__global__ __launch_bounds__(256) void k_hred(
    const float* __restrict__ h_part, float* __restrict__ h)
{
    const size_t idx = (size_t)blockIdx.x * 256 + threadIdx.x;
    const size_t N = (size_t)NROW * D_H;
    float s = 0.f;
    #pragma unroll
    for (int kc = 0; kc < KCHUNKS; ++kc) s += h_part[kc * N + idx];
    h[idx] = s;
}

// ---------------------------------------------------------------------------
// Kernel 2: q/k/v projections.
// ---------------------------------------------------------------------------
template <bool SPLIT>
__global__ __launch_bounds__(192) void k_qkv(
    const float* __restrict__ hin,
    const float* __restrict__ Wk,  const float* __restrict__ Wq,  const float* __restrict__ Wv,
    const float* __restrict__ Wks, const float* __restrict__ Wqs, const float* __restrict__ Wvs,
    const float* __restrict__ Wke, const float* __restrict__ Wqe, const float* __restrict__ Wve,
    u16* __restrict__ q_hi, u16* __restrict__ q_lo,
    u16* __restrict__ k_hi, u16* __restrict__ k_lo,
    u16* __restrict__ vT)
{
    __shared__ float hr[D_H];
    const int bid = blockIdx.x;
    const int b = bid / T_TOT, t = bid % T_TOT;
    const int tid = threadIdx.x;

    const float* hrow = hin + ((size_t)b * T_TOT + t) * D_H;
    if (tid < D_H) hr[tid] = hrow[tid];
    __syncthreads();

    const int which = tid >> 6, j = tid & 63;
    const float* W;
    if (t < S_LEN)               W = which == 0 ? Wks : (which == 1 ? Wqs : Wvs);
    else if (t >= T_TOT - S_LEN) W = which == 0 ? Wke : (which == 1 ? Wqe : Wve);
    else                         W = which == 0 ? Wk  : (which == 1 ? Wq  : Wv);

    float acc = 0.f;
    #pragma unroll
    for (int d = 0; d < D_H; ++d) acc += hr[d] * W[d * D_H + j];

    const size_t idx = ((size_t)b * T_TOT + t) * D_H + j;
    u16 hi = f2bf(acc);
    if (which == 0) {
        k_hi[idx] = hi;
        if (SPLIT) k_lo[idx] = f2bf(acc - bf2f(hi));
    } else if (which == 1) {
        q_hi[idx] = hi;
        if (SPLIT) q_lo[idx] = f2bf(acc - bf2f(hi));
    } else {
        vT[((size_t)b * D_H + j) * T_TOT + t] = hi;
    }
}

// ---------------------------------------------------------------------------
// k_score2c (iter 0): pass 0 = dense QK^T -> per-16-tile sigmoid sums (csum)
// + CAUSAL-ONLY logits store (NT). pass 1 = lint = q.cope (dense, NT store).
// 3-term split precision. Grid (36, 36, 2); wave 16t x 64s.
// ---------------------------------------------------------------------------
__global__ __launch_bounds__(256) void k_score2c(
    const u16* __restrict__ a_hi, const u16* __restrict__ a_lo,
    const u16* __restrict__ k_hi, const u16* __restrict__ k_lo,
    const u16* __restrict__ c_hi, const u16* __restrict__ c_lo,
    float* __restrict__ logits, float* __restrict__ lint,
    float* __restrict__ csum)
{
    const int b  = blockIdx.z;
    const int s0 = blockIdx.x * 64;
    const int wid = threadIdx.x >> 6;
    const int t0 = blockIdx.y * 64 + wid * 16;
    const int wt_max = t0 + 15;
    const int lane = threadIdx.x & 63;
    const int l15 = lane & 15, lg4 = lane >> 4;

    const size_t a_off = ((size_t)(b * T_TOT + t0 + l15)) * D_H + 8 * lg4;
    const short8 ah0 = *(const short8*)(a_hi + a_off);
    const short8 ah1 = *(const short8*)(a_hi + a_off + 32);
    const short8 al0 = *(const short8*)(a_lo + a_off);
    const short8 al1 = *(const short8*)(a_lo + a_off + 32);

    const size_t orow_off = ((size_t)(b * T_TOT + t0 + 4 * lg4)) * T_TOT + s0 + l15;

    // ---- pass 0: logits (causal store) + csum (dense) ----
    {
        const u16* bh = k_hi + (size_t)b * (T_TOT * D_H);
        const u16* bl = k_lo + (size_t)b * (T_TOT * D_H);
        float* o = logits + orow_off;
        #pragma unroll
        for (int ni = 0; ni < 4; ++ni) {
            const size_t b_off = ((size_t)(s0 + ni * 16 + l15)) * D_H + 8 * lg4;
            short8 bh0 = *(const short8*)(bh + b_off);
            short8 bh1 = *(const short8*)(bh + b_off + 32);
            short8 bl0 = *(const short8*)(bl + b_off);
            short8 bl1 = *(const short8*)(bl + b_off + 32);
            f32x4 acc = {0.f, 0.f, 0.f, 0.f};
            acc = __builtin_amdgcn_mfma_f32_16x16x32_bf16(al0, bh0, acc, 0, 0, 0);
            acc = __builtin_amdgcn_mfma_f32_16x16x32_bf16(al1, bh1, acc, 0, 0, 0);
            acc = __builtin_amdgcn_mfma_f32_16x16x32_bf16(ah0, bl0, acc, 0, 0, 0);
            acc = __builtin_amdgcn_mfma_f32_16x16x32_bf16(ah1, bl1, acc, 0, 0, 0);
            acc = __builtin_amdgcn_mfma_f32_16x16x32_bf16(ah0, bh0, acc, 0, 0, 0);
            acc = __builtin_amdgcn_mfma_f32_16x16x32_bf16(ah1, bh1, acc, 0, 0, 0);
            const int c16 = (s0 >> 4) + ni;
            #pragma unroll
            for (int r = 0; r < 4; ++r) {
                float g = 1.f / (1.f + __expf(-acc[r]));
                g += __shfl_xor(g, 1); g += __shfl_xor(g, 2);
                g += __shfl_xor(g, 4); g += __shfl_xor(g, 8);
                if (l15 == 0)
                    csum[((size_t)(b * T_TOT + t0 + 4 * lg4 + r)) * NT16 + c16] = g;
            }
            if (s0 + ni * 16 <= wt_max) {
                #pragma unroll
                for (int r = 0; r < 4; ++r)
                    __builtin_nontemporal_store(acc[r], &o[(size_t)r * T_TOT + ni * 16]);
            }
        }
    }

    // ---- pass 1: lint (dense) ----
    {
        float* o = lint + orow_off;
        #pragma unroll
        for (int ni = 0; ni < 4; ++ni) {
            const size_t b_off = ((size_t)(s0 + ni * 16 + l15)) * D_H + 8 * lg4;
            short8 bh0 = *(const short8*)(c_hi + b_off);
            short8 bh1 = *(const short8*)(c_hi + b_off + 32);
            short8 bl0 = *(const short8*)(c_lo + b_off);
            short8 bl1 = *(const short8*)(c_lo + b_off + 32);
            f32x4 acc = {0.f, 0.f, 0.f, 0.f};
            acc = __builtin_amdgcn_mfma_f32_16x16x32_bf16(al0, bh0, acc, 0, 0, 0);
            acc = __builtin_amdgcn_mfma_f32_16x16x32_bf16(al1, bh1, acc, 0, 0, 0);
            acc = __builtin_amdgcn_mfma_f32_16x16x32_bf16(ah0, bl0, acc, 0, 0, 0);
            acc = __builtin_amdgcn_mfma_f32_16x16x32_bf16(ah1, bl1, acc, 0, 0, 0);
            acc = __builtin_amdgcn_mfma_f32_16x16x32_bf16(ah0, bh0, acc, 0, 0, 0);
            acc = __builtin_amdgcn_mfma_f32_16x16x32_bf16(ah1, bh1, acc, 0, 0, 0);
            #pragma unroll
            for (int r = 0; r < 4; ++r)
                __builtin_nontemporal_store(acc[r], &o[(size_t)r * T_TOT + ni * 16]);
        }
    }
}

// ---------------------------------------------------------------------------
// k_csum: totalv[row] = sum of csum tiles. One wave per row, coalesced.
// ---------------------------------------------------------------------------
__global__ __launch_bounds__(256) void k_csum(
    const float* __restrict__ csum, float* __restrict__ totalv)
{
    const int row = blockIdx.x * 4 + (threadIdx.x >> 6);
    const int lane = threadIdx.x & 63;
    const size_t base = (size_t)row * NT16;
    float v = csum[base + lane] + csum[base + 64 + lane];
    if (128 + lane < NT16) v += csum[base + 128 + lane];
    #pragma unroll
    for (int off = 32; off > 0; off >>= 1) v += __shfl_xor(v, off);
    if (lane == 0) totalv[row] = v;
}

// ---------------------------------------------------------------------------
// Row kernel (iter 0): CoPE scan + bias + softmax, causal-only traffic.
// total from totalv; causal logits; lint loaded only up to total+2.
// Writes p (bf16) zero-padded to the 32-aligned boundary (k_pv reads 32-wide).
// ---------------------------------------------------------------------------
__global__ __launch_bounds__(256) void k_erow(
    const float* __restrict__ logits,
    const float* __restrict__ lint,
    const float* __restrict__ totalv,
    float* __restrict__ pbase)
{
    __shared__ float lg[T_TOT];
    __shared__ float extra[2 * T_TOT];
    __shared__ float wtot[4], wmax[4], wsum[4];

    const int row = blockIdx.x;
    const int t = row % T_TOT;
    const int Lt16 = (t | 15) + 1;               // causal, 16-aligned
    const int Lw = min((Lt16 + 31) & ~31, T_TOT); // 32-aligned write bound (k_pv tail)
    const int tid = threadIdx.x;
    const int lane = tid & 63, wid = tid >> 6;
    const float* lrow = logits + (size_t)row * T_TOT;
    const float tot = totalv[row];
    const int Lc = min((int)tot + 2, T_TOT);     // lint columns ever gathered

    for (int s = tid; s < Lt16; s += 256) lg[s] = lrow[s];
    {
        const float* lintrow = lint + (size_t)row * T_TOT;
        for (int s = tid; s < Lc; s += 256) extra[T_TOT + s] = lintrow[s];
    }
    __syncthreads();

    // gates (causal only; masked g=0) + block-wide exclusive prefix
    {
        const int base = tid * CH;
        float gv[CH];
        float lsum = 0.f;
        #pragma unroll
        for (int u = 0; u < CH; ++u) {
            const int s = base + u;
            float g = (s <= t) ? 1.f / (1.f + expf(-lg[s])) : 0.f;
            gv[u] = g;
            lsum += g;
        }
        float cs = lsum;
        #pragma unroll
        for (int off = 1; off < 64; off <<= 1) {
            float n = __shfl_up(cs, off);
            if (lane >= off) cs += n;
        }
        if (lane == 63) wtot[wid] = cs;
        __syncthreads();
        float pre = 0.f;
        #pragma unroll
        for (int w = 0; w < 4; ++w) {
            float vv = wtot[w];
            if (w < wid) pre += vv;
        }
        float run = pre + cs - lsum;
        #pragma unroll
        for (int u = 0; u < CH; ++u) {
            const int s = base + u;
            if (s <= t) {
                float p = fminf(fmaxf(tot - run, 0.f), (float)(T_TOT - 1));
                extra[s] = p;
            }
            run += gv[u];
        }
        __syncthreads();
    }

    float scv[CH];
    float mx = -3.4e38f;
    #pragma unroll
    for (int r = 0; r < CH; ++r) {
        int sidx = tid + 256 * r;
        float sc = -3.4e38f;
        if (sidx <= t) {
            sc = lg[sidx] * SCALE;
            float p = extra[sidx];
            float pf = floorf(p);
            int fi = (int)pf;
            int ci = (int)ceilf(p);
            float w = p - pf;
            sc += extra[T_TOT + ci] * w + extra[T_TOT + fi] * (1.f - w);
            mx = fmaxf(mx, sc);
        }
        scv[r] = sc;
    }
    #pragma unroll
    for (int off = 32; off > 0; off >>= 1) mx = fmaxf(mx, __shfl_xor(mx, off));
    if (lane == 0) wmax[wid] = mx;
    __syncthreads();
    mx = fmaxf(fmaxf(wmax[0], wmax[1]), fmaxf(wmax[2], wmax[3]));

    float pvv[CH];
    float psum = 0.f;
    #pragma unroll
    for (int r = 0; r < CH; ++r) {
        int sidx = tid + 256 * r;
        float pv = 0.f;
        if (sidx <= t) { pv = expf(scv[r] - mx); psum += pv; }
        pvv[r] = pv;
    }
    #pragma unroll
    for (int off = 32; off > 0; off >>= 1) psum += __shfl_xor(psum, off);
    if (lane == 0) wsum[wid] = psum;
    __syncthreads();
    const float inv = 1.f / (wsum[0] + wsum[1] + wsum[2] + wsum[3]);

    u16* prow = (u16*)(pbase + (size_t)row * T_TOT);
    #pragma unroll
    for (int r = 0; r < CH; ++r) {
        int sidx = tid + 256 * r;
        if (sidx < Lw) prow[sidx] = f2bf(pvv[r] * inv);   // zeros beyond t
    }
}

// ---------------------------------------------------------------------------
// PV GEMM, s-split (iter 0): partial O over an s-chunk; merged by k_pvmerge.
// ---------------------------------------------------------------------------
__global__ __launch_bounds__(256) void k_pv(
    const float* __restrict__ pbuf, const u16* __restrict__ vT,
    float* __restrict__ opart)
{
    const int b  = blockIdx.z;
    const int scn = blockIdx.y;
    const int bx = blockIdx.x;
    const int t0 = bx * 16;
    const int sstart = scn * FCH;
    const int send = min(sstart + FCH, t0 + 16);
    if (sstart >= send) return;

    const int j0 = (threadIdx.x >> 6) * 16;
    const int lane = threadIdx.x & 63;
    const int l15 = lane & 15, lg4 = lane >> 4;

    const u16* pb = (const u16*)pbuf
        + ((size_t)(b * T_TOT + t0 + l15)) * (2 * (size_t)T_TOT) + 8 * lg4;
    const u16* vb = vT + ((size_t)(b * D_H + j0 + l15)) * T_TOT + 8 * lg4;

    f32x4 a0 = {}, a1 = {}, a2 = {}, a3 = {};
    int s = sstart;
    for (; s + 128 <= send; s += 128) {
        short8 p0 = *(const short8*)(pb + s);
        short8 v0 = *(const short8*)(vb + s);
        short8 p1 = *(const short8*)(pb + s + 32);
        short8 v1 = *(const short8*)(vb + s + 32);
        short8 p2 = *(const short8*)(pb + s + 64);
        short8 v2 = *(const short8*)(vb + s + 64);
        short8 p3 = *(const short8*)(pb + s + 96);
        short8 v3 = *(const short8*)(vb + s + 96);
        a0 = __builtin_amdgcn_mfma_f32_16x16x32_bf16(p0, v0, a0, 0, 0, 0);
        a1 = __builtin_amdgcn_mfma_f32_16x16x32_bf16(p1, v1, a1, 0, 0, 0);
        a2 = __builtin_amdgcn_mfma_f32_16x16x32_bf16(p2, v2, a2, 0, 0, 0);
        a3 = __builtin_amdgcn_mfma_f32_16x16x32_bf16(p3, v3, a3, 0, 0, 0);
    }
    for (; s < send; s += 32) {
        short8 p0 = *(const short8*)(pb + s);
        short8 v0 = *(const short8*)(vb + s);
        a0 = __builtin_amdgcn_mfma_f32_16x16x32_bf16(p0, v0, a0, 0, 0, 0);
    }
    f32x4 acc = (a0 + a1) + (a2 + a3);
    float* ob = opart + (((size_t)(b * NTBLK + bx)) * NSC + scn) * (TB * D_H)
              + (size_t)(4 * lg4) * D_H + j0 + l15;
    #pragma unroll
    for (int r = 0; r < 4; ++r) ob[(size_t)r * D_H] = acc[r];
}

__global__ __launch_bounds__(256) void k_pvmerge(
    const float* __restrict__ opart, float* __restrict__ outp)
{
    const int bid = blockIdx.x;
    const int b = bid / NTBLK, bx = bid % NTBLK;
    const int t0 = bx * 16, t_max = t0 + 15;
    const int tid = threadIdx.x;
    const int tl = tid >> 4, j4 = (tid & 15) * 4;

    float4 acc = {0.f, 0.f, 0.f, 0.f};
    for (int scn = 0; scn < NSC; ++scn) {
        if (scn * FCH <= t_max) {
            const float4 v = *(const float4*)&opart[
                (((size_t)(b * NTBLK + bx)) * NSC + scn) * (TB * D_H) + tl * D_H + j4];
            acc.x += v.x; acc.y += v.y; acc.z += v.z; acc.w += v.w;
        }
    }
    *(float4*)&outp[((size_t)(b * T_TOT + t0 + tl)) * D_H + j4] = acc;
}

// ---------------------------------------------------------------------------
// Flash attention iter 1, s-split, online softmax, barrier-free.
// Grid (144, 8, 2); each wave owns 72 cols, writes its own {m,d,o} partial.
// ---------------------------------------------------------------------------
__global__ __launch_bounds__(256) void k_fattn1s(
    const u16* __restrict__ q_hi, const u16* __restrict__ k_hi,
    const u16* __restrict__ vT,
    float* __restrict__ fM, float* __restrict__ fD, float* __restrict__ fO)
{
    __shared__ u16 pstage[4][TB][40];

    const int b   = blockIdx.z;
    const int scn = blockIdx.y;
    const int bx  = blockIdx.x;
    const int t0 = bx * TB;
    const int t_max = t0 + TB - 1;
    if (scn * FCH > t_max) return;

    const int tid = threadIdx.x;
    const int wid = tid >> 6;
    const int lane = tid & 63;
    const int l15 = lane & 15, lg4 = lane >> 4;

    const size_t a_off = ((size_t)(b * T_TOT + t0 + l15)) * D_H + 8 * lg4;
    const short8 ah0 = *(const short8*)(q_hi + a_off);
    const short8 ah1 = *(const short8*)(q_hi + a_off + 32);
    const u16* kh = k_hi + (size_t)b * (T_TOT * D_H);

    const int w_lo  = scn * FCH + wid * (FCH / 4);     // 72-wide per wave
    const int w_end = min(w_lo + FCH / 4, t_max + 1);  // exclusive

    float m[4]   = {-3.0e38f, -3.0e38f, -3.0e38f, -3.0e38f};
    float den[4] = {0.f, 0.f, 0.f, 0.f};
    f32x4 oacc[4] = {};

    for (int s32 = w_lo; s32 < w_end; s32 += 32) {
        f32x4 acc0 = {0.f, 0.f, 0.f, 0.f};
        f32x4 acc1 = {0.f, 0.f, 0.f, 0.f};
        const bool ir1 = (s32 + 16) < w_end;
        {
            const size_t b_off = ((size_t)(s32 + l15)) * D_H + 8 * lg4;
            short8 b0 = *(const short8*)(kh + b_off);
            short8 b1 = *(const short8*)(kh + b_off + 32);
            acc0 = __builtin_amdgcn_mfma_f32_16x16x32_bf16(ah0, b0, acc0, 0, 0, 0);
            acc0 = __builtin_amdgcn_mfma_f32_16x16x32_bf16(ah1, b1, acc0, 0, 0, 0);
        }
        if (ir1) {
            const size_t b_off = ((size_t)(s32 + 16 + l15)) * D_H + 8 * lg4;
            short8 b0 = *(const short8*)(kh + b_off);
            short8 b1 = *(const short8*)(kh + b_off + 32);
            acc1 = __builtin_amdgcn_mfma_f32_16x16x32_bf16(ah0, b0, acc1, 0, 0, 0);
            acc1 = __builtin_amdgcn_mfma_f32_16x16x32_bf16(ah1, b1, acc1, 0, 0, 0);
        }
        #pragma unroll
        for (int r = 0; r < 4; ++r) {
            const int tl = 4 * lg4 + r;
            const int c0 = s32 + l15, c1 = s32 + 16 + l15;
            const bool v0 = (c0 < w_end) && (c0 <= t0 + tl);
            const bool v1 = ir1 && (c1 < w_end) && (c1 <= t0 + tl);
            const float sc0 = acc0[r] * SCALE;
            const float sc1 = acc1[r] * SCALE;
            float tmx = fmaxf(v0 ? sc0 : -3.0e38f, v1 ? sc1 : -3.0e38f);
            tmx = fmaxf(tmx, __shfl_xor(tmx, 1));
            tmx = fmaxf(tmx, __shfl_xor(tmx, 2));
            tmx = fmaxf(tmx, __shfl_xor(tmx, 4));
            tmx = fmaxf(tmx, __shfl_xor(tmx, 8));
            const float mn = fmaxf(m[r], tmx);
            const float scl = __expf(m[r] - mn);
            m[r] = mn;
            const float p0 = v0 ? __expf(sc0 - mn) : 0.f;
            const float p1 = v1 ? __expf(sc1 - mn) : 0.f;
            float ps = p0 + p1;
            ps += __shfl_xor(ps, 1); ps += __shfl_xor(ps, 2);
            ps += __shfl_xor(ps, 4); ps += __shfl_xor(ps, 8);
            den[r] = den[r] * scl + ps;
            #pragma unroll
            for (int j = 0; j < 4; ++j) oacc[j][r] *= scl;
            pstage[wid][tl][l15] = f2bf(p0);
            pstage[wid][tl][16 + l15] = f2bf(p1);
        }
        const short8 pa = *(const short8*)&pstage[wid][l15][8 * lg4];
        #pragma unroll
        for (int j = 0; j < 4; ++j) {
            const size_t v_off = ((size_t)(b * D_H + j * 16 + l15)) * T_TOT + s32 + 8 * lg4;
            short8 bv = *(const short8*)(vT + v_off);
            oacc[j] = __builtin_amdgcn_mfma_f32_16x16x32_bf16(pa, bv, oacc[j], 0, 0, 0);
        }
    }

    const size_t pidx = ((size_t)(b * NTBLK + bx)) * NPART + scn * 4 + wid;
    if (l15 == 0) {
        #pragma unroll
        for (int r = 0; r < 4; ++r) {
            fM[pidx * TB + 4 * lg4 + r] = m[r];
            fD[pidx * TB + 4 * lg4 + r] = den[r];
        }
    }
    #pragma unroll
    for (int j = 0; j < 4; ++j)
        #pragma unroll
        for (int r = 0; r < 4; ++r)
            fO[pidx * (TB * D_H) + (size_t)(4 * lg4 + r) * D_H + j * 16 + l15] = oacc[j][r];
}

__global__ __launch_bounds__(256) void k_fmerge(
    const float* __restrict__ fM, const float* __restrict__ fD,
    const float* __restrict__ fO, float* __restrict__ outp)
{
    const int bid = blockIdx.x;
    const int b = bid / NTBLK, bx = bid % NTBLK;
    const int t0 = bx * 16, t_max = t0 + 15;
    const int tid = threadIdx.x;
    const int tl = tid >> 4, j4 = (tid & 15) * 4;
    const size_t pb = (size_t)bid * NPART;

    float M = -3.0e38f;
    #pragma unroll
    for (int c = 0; c < NPART; ++c)
        if ((c >> 2) * FCH <= t_max) M = fmaxf(M, fM[(pb + c) * TB + tl]);

    float D = 0.f;
    float4 O = {0.f, 0.f, 0.f, 0.f};
    for (int c = 0; c < NPART; ++c) {
        if ((c >> 2) * FCH <= t_max) {
            const float w = __expf(fM[(pb + c) * TB + tl] - M);
            D += w * fD[(pb + c) * TB + tl];
            const float4 ov = *(const float4*)&fO[(pb + c) * (TB * D_H) + tl * D_H + j4];
            O.x += w * ov.x; O.y += w * ov.y; O.z += w * ov.z; O.w += w * ov.w;
        }
    }
    const float inv = 1.f / D;
    float4 res; res.x = O.x * inv; res.y = O.y * inv; res.z = O.z * inv; res.w = O.w * inv;
    *(float4*)&outp[((size_t)(b * T_TOT + t0 + tl)) * D_H + j4] = res;
}

// ---------------------------------------------------------------------------
extern "C" void kernel_launch(void* const* d_in, const int* in_sizes, int n_in,
                              void* d_out, int out_size, void* d_ws, size_t ws_size,
                              hipStream_t stream) {
    const float* x    = (const float*)d_in[0];
    const float* Wh   = (const float*)d_in[1];
    const float* Whs  = (const float*)d_in[2];
    const float* Whe  = (const float*)d_in[3];
    const float* Wk   = (const float*)d_in[4];
    const float* Wq   = (const float*)d_in[5];
    const float* Wv   = (const float*)d_in[6];
    const float* Wks  = (const float*)d_in[7];
    const float* Wqs  = (const float*)d_in[8];
    const float* Wvs  = (const float*)d_in[9];
    const float* Wke  = (const float*)d_in[10];
    const float* Wqe  = (const float*)d_in[11];
    const float* Wve  = (const float*)d_in[12];
    const float* ln_g  = (const float*)d_in[13];
    const float* ln_b  = (const float*)d_in[14];
    const float* ln_gs = (const float*)d_in[15];
    const float* ln_bs = (const float*)d_in[16];
    const float* ln_ge = (const float*)d_in[17];
    const float* ln_be = (const float*)d_in[18];
    const float* cope  = (const float*)d_in[19];

    float* out = (float*)d_out;

    const size_t N = (size_t)NROW * D_H;        // 294912
    char* W = (char*)d_ws;
    u16* xn_hi  = (u16*)W;    W += (size_t)NROW * D_IN * 2;
    u16* xn_lo  = (u16*)W;    W += (size_t)NROW * D_IN * 2;
    u16* wT_hi  = (u16*)W;    W += (size_t)3 * D_H * D_IN * 2;
    u16* wT_lo  = (u16*)W;    W += (size_t)3 * D_H * D_IN * 2;
    float* h    = (float*)W;  W += N * 4;
    u16* q_hi   = (u16*)W;    W += N * 2;
    u16* q_lo   = (u16*)W;    W += N * 2;
    u16* k_hi   = (u16*)W;    W += N * 2;
    u16* k_lo   = (u16*)W;    W += N * 2;
    u16* vT     = (u16*)W;    W += N * 2;
    u16* cT_hi  = (u16*)W;    W += (size_t)T_TOT * D_H * 2;
    u16* cT_lo  = (u16*)W;    W += (size_t)T_TOT * D_H * 2;
    float* logits = (float*)W; W += (size_t)BATCH * T_TOT * T_TOT * 4;
    float* lint   = (float*)W; W += (size_t)BATCH * T_TOT * T_TOT * 4;  // also p / h_part
    float* csum   = (float*)W; W += (size_t)NROW * NT16 * 4;
    float* totalv = (float*)W; W += (size_t)NROW * 4;
    float* mem1   = (float*)W; W += N * 4;
    float* opart  = (float*)W; W += (size_t)BATCH * NTBLK * NSC * TB * D_H * 4;
    float* fM     = (float*)W; W += (size_t)BATCH * NTBLK * NPART * TB * 4;
    float* fD     = (float*)W; W += (size_t)BATCH * NTBLK * NPART * TB * 4;
    float* fO     = (float*)W; W += (size_t)BATCH * NTBLK * NPART * TB * D_H * 4;

    float* h_part = lint;   // reused before lint is written (8 * N floats)

    k_ln<<<NROW, 256, 0, stream>>>(x, ln_g, ln_b, ln_gs, ln_bs, ln_ge, ln_be,
                                   xn_hi, xn_lo);
    k_prep<<<(WPREP_N + T_TOT * D_H + 255) / 256, 256, 0, stream>>>(
        Wh, Whs, Whe, cope, wT_hi, wT_lo, cT_hi, cT_lo);
    k_hgemm<<<dim3(NROW / 64, KCHUNKS), 256, 0, stream>>>(xn_hi, xn_lo, wT_hi, wT_lo, h_part);
    k_hred<<<(int)(N / 256), 256, 0, stream>>>(h_part, h);

    // iteration 0 (CoPE)
    k_qkv<true><<<NROW, 192, 0, stream>>>(h, Wk, Wq, Wv, Wks, Wqs, Wvs, Wke, Wqe, Wve,
                                          q_hi, q_lo, k_hi, k_lo, vT);
    k_score2c<<<dim3(T_TOT / 64, T_TOT / 64, BATCH), 256, 0, stream>>>(
        q_hi, q_lo, k_hi, k_lo, cT_hi, cT_lo, logits, lint, csum);
    k_csum<<<NROW / 4, 256, 0, stream>>>(csum, totalv);
    k_erow<<<NROW, 256, 0, stream>>>(logits, lint, totalv, lint);
    k_pv<<<dim3(NTBLK, NSC, BATCH), 256, 0, stream>>>(lint, vT, opart);
    k_pvmerge<<<BATCH * NTBLK, 256, 0, stream>>>(opart, mem1);

    // iteration 1 (plain causal, s-split online flash)
    k_qkv<false><<<NROW, 192, 0, stream>>>(mem1, Wk, Wq, Wv, Wks, Wqs, Wvs, Wke, Wqe, Wve,
                                           q_hi, q_lo, k_hi, k_lo, vT);
    k_fattn1s<<<dim3(NTBLK, NSC, BATCH), 256, 0, stream>>>(q_hi, k_hi, vT, fM, fD, fO);
    k_fmerge<<<BATCH * NTBLK, 256, 0, stream>>>(fM, fD, fO, out);
}

// Round 13
// 194.701 us; speedup vs baseline: 1.0096x; 1.0096x over previous
//
#include <hip/hip_runtime.h>

#define T_TOT 2304
#define S_LEN 128
#define D_IN  1024
#define D_H   64
#define BATCH 2
#define NROW  (BATCH * T_TOT)
#define CH    (T_TOT / 256)   // 9
#define SCALE 0.125f
#define KCHUNKS 8
#define KCW   (D_IN / KCHUNKS)   // 128
#define TB    16                 // t-rows per flash block
#define FCH   288                // s-chunk width (flash + pv split)
#define NSC   8                  // number of s-chunks
#define NTBLK (T_TOT / TB)       // 144
#define NT16  (T_TOT / 16)       // 144 col-tiles
#define NPART (NSC * 4)          // 32 partials per t-block

typedef unsigned short u16;
typedef __attribute__((ext_vector_type(8))) short short8;
typedef __attribute__((ext_vector_type(4))) float f32x4;
typedef __attribute__((ext_vector_type(4))) unsigned short u16x4;

static __device__ __forceinline__ u16 f2bf(float f) {
    unsigned u = __float_as_uint(f);
    unsigned r = (u + 0x7fffu + ((u >> 16) & 1u)) >> 16;
    return (u16)r;
}
static __device__ __forceinline__ float bf2f(u16 s) {
    return __uint_as_float((unsigned)s << 16);
}

// ---------------------------------------------------------------------------
// Kernel 1a: LayerNorm(x_row) -> xn hi/lo (split bf16). One block (256)/row.
// ---------------------------------------------------------------------------
__global__ __launch_bounds__(256) void k_ln(
    const float* __restrict__ x,
    const float* __restrict__ ln_g,  const float* __restrict__ ln_b,
    const float* __restrict__ ln_gs, const float* __restrict__ ln_bs,
    const float* __restrict__ ln_ge, const float* __restrict__ ln_be,
    u16* __restrict__ xn_hi, u16* __restrict__ xn_lo)
{
    __shared__ float red1[256], red2[256];
    const int row = blockIdx.x;
    const int t = row % T_TOT;
    const int tid = threadIdx.x;

    const float *gg, *bb;
    if (t < S_LEN)               { gg = ln_gs; bb = ln_bs; }
    else if (t >= T_TOT - S_LEN) { gg = ln_ge; bb = ln_be; }
    else                         { gg = ln_g;  bb = ln_b;  }

    const float4 xv = *(const float4*)(x + (size_t)row * D_IN + 4 * tid);
    float s  = xv.x + xv.y + xv.z + xv.w;
    float s2 = xv.x * xv.x + xv.y * xv.y + xv.z * xv.z + xv.w * xv.w;
    red1[tid] = s; red2[tid] = s2; __syncthreads();
    for (int off = 128; off > 0; off >>= 1) {
        if (tid < off) { red1[tid] += red1[tid + off]; red2[tid] += red2[tid + off]; }
        __syncthreads();
    }
    const float mean = red1[0] * (1.f / D_IN);
    const float var  = red2[0] * (1.f / D_IN) - mean * mean;
    const float rstd = rsqrtf(var + 1e-5f);

    const float4 gv = *(const float4*)(gg + 4 * tid);
    const float4 bv = *(const float4*)(bb + 4 * tid);
    float o0 = (xv.x - mean) * rstd * gv.x + bv.x;
    float o1 = (xv.y - mean) * rstd * gv.y + bv.y;
    float o2 = (xv.z - mean) * rstd * gv.z + bv.z;
    float o3 = (xv.w - mean) * rstd * gv.w + bv.w;

    u16x4 hv, lv;
    hv[0] = f2bf(o0); lv[0] = f2bf(o0 - bf2f(hv[0]));
    hv[1] = f2bf(o1); lv[1] = f2bf(o1 - bf2f(hv[1]));
    hv[2] = f2bf(o2); lv[2] = f2bf(o2 - bf2f(hv[2]));
    hv[3] = f2bf(o3); lv[3] = f2bf(o3 - bf2f(hv[3]));
    *(u16x4*)(xn_hi + (size_t)row * D_IN + 4 * tid) = hv;
    *(u16x4*)(xn_lo + (size_t)row * D_IN + 4 * tid) = lv;
}

// ---------------------------------------------------------------------------
// Kernel 1b: prep — transpose+split Wh/Whs/Whe, and split cope_emb^T
// ---------------------------------------------------------------------------
#define WPREP_N (3 * D_H * D_IN)
__global__ __launch_bounds__(256) void k_prep(
    const float* __restrict__ Wh, const float* __restrict__ Whs, const float* __restrict__ Whe,
    const float* __restrict__ cope,
    u16* __restrict__ wT_hi, u16* __restrict__ wT_lo,
    u16* __restrict__ cT_hi, u16* __restrict__ cT_lo)
{
    const int gid = blockIdx.x * 256 + threadIdx.x;
    if (gid < WPREP_N) {
        const int seg = gid >> 16;
        const int o = gid & 65535;
        const int j = o >> 10, k = o & 1023;
        const float* W = seg == 0 ? Wh : (seg == 1 ? Whs : Whe);
        const float f = W[k * D_H + j];
        const u16 hi = f2bf(f);
        wT_hi[gid] = hi;
        wT_lo[gid] = f2bf(f - bf2f(hi));
    } else {
        const int idx = gid - WPREP_N;
        if (idx < T_TOT * D_H) {
            const int n = idx >> 6, d = idx & 63;
            const float f = cope[(size_t)d * T_TOT + n];
            const u16 hi = f2bf(f);
            cT_hi[idx] = hi;
            cT_lo[idx] = f2bf(f - bf2f(hi));
        }
    }
}

// ---------------------------------------------------------------------------
// Kernel 1c: h_part[kc] = LN(x)[:, kc*128:+128] @ W_seg[kc chunk]  (MFMA, split)
// ---------------------------------------------------------------------------
__global__ __launch_bounds__(256) void k_hgemm(
    const u16* __restrict__ xn_hi, const u16* __restrict__ xn_lo,
    const u16* __restrict__ wT_hi, const u16* __restrict__ wT_lo,
    float* __restrict__ h_part)
{
    const int tile = blockIdx.x;              // 0..71
    const int kc   = blockIdx.y;              // 0..7
    const int k0   = kc * KCW;
    const int tt = tile % 36;
    const int seg = tt < 2 ? 1 : (tt >= 34 ? 2 : 0);

    __shared__ u16 Bh[64 * KCW];
    __shared__ u16 Bl[64 * KCW];

    const int tid = threadIdx.x;
    {
        const int r = tid >> 2;
        const int c0 = (tid & 3) * 32;
        const u16* sh = wT_hi + ((size_t)seg * D_H + r) * D_IN + k0 + c0;
        const u16* sl = wT_lo + ((size_t)seg * D_H + r) * D_IN + k0 + c0;
        const int sw = (r & 7) << 3;
        #pragma unroll
        for (int u = 0; u < 4; ++u) {
            const int col = c0 + 8 * u;
            *(short8*)&Bh[r * KCW + (col ^ sw)] = *(const short8*)(sh + 8 * u);
            *(short8*)&Bl[r * KCW + (col ^ sw)] = *(const short8*)(sl + 8 * u);
        }
    }
    __syncthreads();

    const int w = tid >> 6;
    const int lane = tid & 63;
    const int l15 = lane & 15, lg4 = lane >> 4;
    const int row0 = tile * 64 + w * 16;

    const size_t abase = (size_t)(row0 + l15) * D_IN + k0 + 8 * lg4;
    f32x4 acc[4] = {};

    #pragma unroll
    for (int kk = 0; kk < KCW / 32; ++kk) {
        short8 ah = *(const short8*)(xn_hi + abase + kk * 32);
        short8 al = *(const short8*)(xn_lo + abase + kk * 32);
        #pragma unroll
        for (int j = 0; j < 4; ++j) {
            const int brow = j * 16 + l15;
            const int col = (kk * 32 + 8 * lg4) ^ ((brow & 7) << 3);
            short8 bh = *(const short8*)&Bh[brow * KCW + col];
            short8 bl = *(const short8*)&Bl[brow * KCW + col];
            acc[j] = __builtin_amdgcn_mfma_f32_16x16x32_bf16(al, bh, acc[j], 0, 0, 0);
            acc[j] = __builtin_amdgcn_mfma_f32_16x16x32_bf16(ah, bl, acc[j], 0, 0, 0);
            acc[j] = __builtin_amdgcn_mfma_f32_16x16x32_bf16(ah, bh, acc[j], 0, 0, 0);
        }
    }
    float* hp = h_part + (size_t)kc * ((size_t)NROW * D_H);
    #pragma unroll
    for (int j = 0; j < 4; ++j)
        #pragma unroll
        for (int r = 0; r < 4; ++r)
            hp[(size_t)(row0 + 4 * lg4 + r) * D_H + j * 16 + l15] = acc[j][r];
}

// ---------------------------------------------------------------------------
// Kernel 1d: h = sum_kc h_part[kc]
// ---------------------------------------------------------------------------
__global__ __launch_bounds__(256) void k_hred(
    const float* __restrict__ h_part, float* __restrict__ h)
{
    const size_t idx = (size_t)blockIdx.x * 256 + threadIdx.x;
    const size_t N = (size_t)NROW * D_H;
    float s = 0.f;
    #pragma unroll
    for (int kc = 0; kc < KCHUNKS; ++kc) s += h_part[kc * N + idx];
    h[idx] = s;
}

// ---------------------------------------------------------------------------
// Kernel 2: q/k/v projections.
// ---------------------------------------------------------------------------
template <bool SPLIT>
__global__ __launch_bounds__(192) void k_qkv(
    const float* __restrict__ hin,
    const float* __restrict__ Wk,  const float* __restrict__ Wq,  const float* __restrict__ Wv,
    const float* __restrict__ Wks, const float* __restrict__ Wqs, const float* __restrict__ Wvs,
    const float* __restrict__ Wke, const float* __restrict__ Wqe, const float* __restrict__ Wve,
    u16* __restrict__ q_hi, u16* __restrict__ q_lo,
    u16* __restrict__ k_hi, u16* __restrict__ k_lo,
    u16* __restrict__ vT)
{
    __shared__ float hr[D_H];
    const int bid = blockIdx.x;
    const int b = bid / T_TOT, t = bid % T_TOT;
    const int tid = threadIdx.x;

    const float* hrow = hin + ((size_t)b * T_TOT + t) * D_H;
    if (tid < D_H) hr[tid] = hrow[tid];
    __syncthreads();

    const int which = tid >> 6, j = tid & 63;
    const float* W;
    if (t < S_LEN)               W = which == 0 ? Wks : (which == 1 ? Wqs : Wvs);
    else if (t >= T_TOT - S_LEN) W = which == 0 ? Wke : (which == 1 ? Wqe : Wve);
    else                         W = which == 0 ? Wk  : (which == 1 ? Wq  : Wv);

    float acc = 0.f;
    #pragma unroll
    for (int d = 0; d < D_H; ++d) acc += hr[d] * W[d * D_H + j];

    const size_t idx = ((size_t)b * T_TOT + t) * D_H + j;
    u16 hi = f2bf(acc);
    if (which == 0) {
        k_hi[idx] = hi;
        if (SPLIT) k_lo[idx] = f2bf(acc - bf2f(hi));
    } else if (which == 1) {
        q_hi[idx] = hi;
        if (SPLIT) q_lo[idx] = f2bf(acc - bf2f(hi));
    } else {
        vT[((size_t)b * D_H + j) * T_TOT + t] = hi;
    }
}

// ---------------------------------------------------------------------------
// k_score2c (iter 0): pass A = lint = q.cope (dense). pass B = dense QK^T ->
// per-16-tile sigmoid sums (csum) + CAUSAL-ONLY logits store. Plain stores so
// recently-written logits stay L2-resident for k_erow (lint pass runs first).
// 3-term split precision. Grid (36, 36, 2); wave 16t x 64s.
// ---------------------------------------------------------------------------
__global__ __launch_bounds__(256) void k_score2c(
    const u16* __restrict__ a_hi, const u16* __restrict__ a_lo,
    const u16* __restrict__ k_hi, const u16* __restrict__ k_lo,
    const u16* __restrict__ c_hi, const u16* __restrict__ c_lo,
    float* __restrict__ logits, float* __restrict__ lint,
    float* __restrict__ csum)
{
    const int b  = blockIdx.z;
    const int s0 = blockIdx.x * 64;
    const int wid = threadIdx.x >> 6;
    const int t0 = blockIdx.y * 64 + wid * 16;
    const int wt_max = t0 + 15;
    const int lane = threadIdx.x & 63;
    const int l15 = lane & 15, lg4 = lane >> 4;

    const size_t a_off = ((size_t)(b * T_TOT + t0 + l15)) * D_H + 8 * lg4;
    const short8 ah0 = *(const short8*)(a_hi + a_off);
    const short8 ah1 = *(const short8*)(a_hi + a_off + 32);
    const short8 al0 = *(const short8*)(a_lo + a_off);
    const short8 al1 = *(const short8*)(a_lo + a_off + 32);

    const size_t orow_off = ((size_t)(b * T_TOT + t0 + 4 * lg4)) * T_TOT + s0 + l15;

    // ---- pass A: lint (dense) ----
    {
        float* o = lint + orow_off;
        #pragma unroll
        for (int ni = 0; ni < 4; ++ni) {
            const size_t b_off = ((size_t)(s0 + ni * 16 + l15)) * D_H + 8 * lg4;
            short8 bh0 = *(const short8*)(c_hi + b_off);
            short8 bh1 = *(const short8*)(c_hi + b_off + 32);
            short8 bl0 = *(const short8*)(c_lo + b_off);
            short8 bl1 = *(const short8*)(c_lo + b_off + 32);
            f32x4 acc = {0.f, 0.f, 0.f, 0.f};
            acc = __builtin_amdgcn_mfma_f32_16x16x32_bf16(al0, bh0, acc, 0, 0, 0);
            acc = __builtin_amdgcn_mfma_f32_16x16x32_bf16(al1, bh1, acc, 0, 0, 0);
            acc = __builtin_amdgcn_mfma_f32_16x16x32_bf16(ah0, bl0, acc, 0, 0, 0);
            acc = __builtin_amdgcn_mfma_f32_16x16x32_bf16(ah1, bl1, acc, 0, 0, 0);
            acc = __builtin_amdgcn_mfma_f32_16x16x32_bf16(ah0, bh0, acc, 0, 0, 0);
            acc = __builtin_amdgcn_mfma_f32_16x16x32_bf16(ah1, bh1, acc, 0, 0, 0);
            #pragma unroll
            for (int r = 0; r < 4; ++r)
                o[(size_t)r * T_TOT + ni * 16] = acc[r];
        }
    }

    // ---- pass B: logits (causal store) + csum (dense) ----
    {
        const u16* bh = k_hi + (size_t)b * (T_TOT * D_H);
        const u16* bl = k_lo + (size_t)b * (T_TOT * D_H);
        float* o = logits + orow_off;
        #pragma unroll
        for (int ni = 0; ni < 4; ++ni) {
            const size_t b_off = ((size_t)(s0 + ni * 16 + l15)) * D_H + 8 * lg4;
            short8 bh0 = *(const short8*)(bh + b_off);
            short8 bh1 = *(const short8*)(bh + b_off + 32);
            short8 bl0 = *(const short8*)(bl + b_off);
            short8 bl1 = *(const short8*)(bl + b_off + 32);
            f32x4 acc = {0.f, 0.f, 0.f, 0.f};
            acc = __builtin_amdgcn_mfma_f32_16x16x32_bf16(al0, bh0, acc, 0, 0, 0);
            acc = __builtin_amdgcn_mfma_f32_16x16x32_bf16(al1, bh1, acc, 0, 0, 0);
            acc = __builtin_amdgcn_mfma_f32_16x16x32_bf16(ah0, bl0, acc, 0, 0, 0);
            acc = __builtin_amdgcn_mfma_f32_16x16x32_bf16(ah1, bl1, acc, 0, 0, 0);
            acc = __builtin_amdgcn_mfma_f32_16x16x32_bf16(ah0, bh0, acc, 0, 0, 0);
            acc = __builtin_amdgcn_mfma_f32_16x16x32_bf16(ah1, bh1, acc, 0, 0, 0);
            const int c16 = (s0 >> 4) + ni;
            #pragma unroll
            for (int r = 0; r < 4; ++r) {
                float g = 1.f / (1.f + __expf(-acc[r]));
                g += __shfl_xor(g, 1); g += __shfl_xor(g, 2);
                g += __shfl_xor(g, 4); g += __shfl_xor(g, 8);
                if (l15 == 0)
                    csum[((size_t)(b * T_TOT + t0 + 4 * lg4 + r)) * NT16 + c16] = g;
            }
            if (s0 + ni * 16 <= wt_max) {
                #pragma unroll
                for (int r = 0; r < 4; ++r)
                    o[(size_t)r * T_TOT + ni * 16] = acc[r];
            }
        }
    }
}

// ---------------------------------------------------------------------------
// k_csum: totalv[row] = sum of csum tiles. One wave per row, coalesced.
// ---------------------------------------------------------------------------
__global__ __launch_bounds__(256) void k_csum(
    const float* __restrict__ csum, float* __restrict__ totalv)
{
    const int row = blockIdx.x * 4 + (threadIdx.x >> 6);
    const int lane = threadIdx.x & 63;
    const size_t base = (size_t)row * NT16;
    float v = csum[base + lane] + csum[base + 64 + lane];
    if (128 + lane < NT16) v += csum[base + 128 + lane];
    #pragma unroll
    for (int off = 32; off > 0; off >>= 1) v += __shfl_xor(v, off);
    if (lane == 0) totalv[row] = v;
}

// ---------------------------------------------------------------------------
// Row kernel (iter 0): CoPE scan + bias + softmax, causal-only traffic.
// total from totalv; causal logits; lint loaded only up to total+2.
// Writes p (bf16) zero-padded to the 32-aligned boundary (k_pv reads 32-wide).
// ---------------------------------------------------------------------------
__global__ __launch_bounds__(256) void k_erow(
    const float* __restrict__ logits,
    const float* __restrict__ lint,
    const float* __restrict__ totalv,
    float* __restrict__ pbase)
{
    __shared__ float lg[T_TOT];
    __shared__ float extra[2 * T_TOT];
    __shared__ float wtot[4], wmax[4], wsum[4];

    const int row = blockIdx.x;
    const int t = row % T_TOT;
    const int Lt16 = (t | 15) + 1;                // causal, 16-aligned
    const int Lw = min((Lt16 + 31) & ~31, T_TOT); // 32-aligned write bound (k_pv tail)
    const int tid = threadIdx.x;
    const int lane = tid & 63, wid = tid >> 6;
    const float* lrow = logits + (size_t)row * T_TOT;
    const float tot = totalv[row];
    const int Lc = min((int)tot + 2, T_TOT);      // lint columns ever gathered

    for (int s = tid; s < Lt16; s += 256) lg[s] = lrow[s];
    {
        const float* lintrow = lint + (size_t)row * T_TOT;
        for (int s = tid; s < Lc; s += 256) extra[T_TOT + s] = lintrow[s];
    }
    __syncthreads();

    // gates (causal only; masked g=0) + block-wide exclusive prefix
    {
        const int base = tid * CH;
        float gv[CH];
        float lsum = 0.f;
        #pragma unroll
        for (int u = 0; u < CH; ++u) {
            const int s = base + u;
            float g = (s <= t) ? 1.f / (1.f + expf(-lg[s])) : 0.f;
            gv[u] = g;
            lsum += g;
        }
        float cs = lsum;
        #pragma unroll
        for (int off = 1; off < 64; off <<= 1) {
            float n = __shfl_up(cs, off);
            if (lane >= off) cs += n;
        }
        if (lane == 63) wtot[wid] = cs;
        __syncthreads();
        float pre = 0.f;
        #pragma unroll
        for (int w = 0; w < 4; ++w) {
            float vv = wtot[w];
            if (w < wid) pre += vv;
        }
        float run = pre + cs - lsum;
        #pragma unroll
        for (int u = 0; u < CH; ++u) {
            const int s = base + u;
            if (s <= t) {
                float p = fminf(fmaxf(tot - run, 0.f), (float)(T_TOT - 1));
                extra[s] = p;
            }
            run += gv[u];
        }
        __syncthreads();
    }

    float scv[CH];
    float mx = -3.4e38f;
    #pragma unroll
    for (int r = 0; r < CH; ++r) {
        int sidx = tid + 256 * r;
        float sc = -3.4e38f;
        if (sidx <= t) {
            sc = lg[sidx] * SCALE;
            float p = extra[sidx];
            float pf = floorf(p);
            int fi = (int)pf;
            int ci = (int)ceilf(p);
            float w = p - pf;
            sc += extra[T_TOT + ci] * w + extra[T_TOT + fi] * (1.f - w);
            mx = fmaxf(mx, sc);
        }
        scv[r] = sc;
    }
    #pragma unroll
    for (int off = 32; off > 0; off >>= 1) mx = fmaxf(mx, __shfl_xor(mx, off));
    if (lane == 0) wmax[wid] = mx;
    __syncthreads();
    mx = fmaxf(fmaxf(wmax[0], wmax[1]), fmaxf(wmax[2], wmax[3]));

    float pvv[CH];
    float psum = 0.f;
    #pragma unroll
    for (int r = 0; r < CH; ++r) {
        int sidx = tid + 256 * r;
        float pv = 0.f;
        if (sidx <= t) { pv = expf(scv[r] - mx); psum += pv; }
        pvv[r] = pv;
    }
    #pragma unroll
    for (int off = 32; off > 0; off >>= 1) psum += __shfl_xor(psum, off);
    if (lane == 0) wsum[wid] = psum;
    __syncthreads();
    const float inv = 1.f / (wsum[0] + wsum[1] + wsum[2] + wsum[3]);

    u16* prow = (u16*)(pbase + (size_t)row * T_TOT);
    #pragma unroll
    for (int r = 0; r < CH; ++r) {
        int sidx = tid + 256 * r;
        if (sidx < Lw) prow[sidx] = f2bf(pvv[r] * inv);   // zeros beyond t
    }
}

// ---------------------------------------------------------------------------
// PV GEMM, s-split (iter 0): partial O over an s-chunk; merged by k_pvmerge.
// ---------------------------------------------------------------------------
__global__ __launch_bounds__(256) void k_pv(
    const float* __restrict__ pbuf, const u16* __restrict__ vT,
    float* __restrict__ opart)
{
    const int b  = blockIdx.z;
    const int scn = blockIdx.y;
    const int bx = blockIdx.x;
    const int t0 = bx * 16;
    const int sstart = scn * FCH;
    const int send = min(sstart + FCH, t0 + 16);
    if (sstart >= send) return;

    const int j0 = (threadIdx.x >> 6) * 16;
    const int lane = threadIdx.x & 63;
    const int l15 = lane & 15, lg4 = lane >> 4;

    const u16* pb = (const u16*)pbuf
        + ((size_t)(b * T_TOT + t0 + l15)) * (2 * (size_t)T_TOT) + 8 * lg4;
    const u16* vb = vT + ((size_t)(b * D_H + j0 + l15)) * T_TOT + 8 * lg4;

    f32x4 a0 = {}, a1 = {}, a2 = {}, a3 = {};
    int s = sstart;
    for (; s + 128 <= send; s += 128) {
        short8 p0 = *(const short8*)(pb + s);
        short8 v0 = *(const short8*)(vb + s);
        short8 p1 = *(const short8*)(pb + s + 32);
        short8 v1 = *(const short8*)(vb + s + 32);
        short8 p2 = *(const short8*)(pb + s + 64);
        short8 v2 = *(const short8*)(vb + s + 64);
        short8 p3 = *(const short8*)(pb + s + 96);
        short8 v3 = *(const short8*)(vb + s + 96);
        a0 = __builtin_amdgcn_mfma_f32_16x16x32_bf16(p0, v0, a0, 0, 0, 0);
        a1 = __builtin_amdgcn_mfma_f32_16x16x32_bf16(p1, v1, a1, 0, 0, 0);
        a2 = __builtin_amdgcn_mfma_f32_16x16x32_bf16(p2, v2, a2, 0, 0, 0);
        a3 = __builtin_amdgcn_mfma_f32_16x16x32_bf16(p3, v3, a3, 0, 0, 0);
    }
    for (; s < send; s += 32) {
        short8 p0 = *(const short8*)(pb + s);
        short8 v0 = *(const short8*)(vb + s);
        a0 = __builtin_amdgcn_mfma_f32_16x16x32_bf16(p0, v0, a0, 0, 0, 0);
    }
    f32x4 acc = (a0 + a1) + (a2 + a3);
    float* ob = opart + (((size_t)(b * NTBLK + bx)) * NSC + scn) * (TB * D_H)
              + (size_t)(4 * lg4) * D_H + j0 + l15;
    #pragma unroll
    for (int r = 0; r < 4; ++r) ob[(size_t)r * D_H] = acc[r];
}

__global__ __launch_bounds__(256) void k_pvmerge(
    const float* __restrict__ opart, float* __restrict__ outp)
{
    const int bid = blockIdx.x;
    const int b = bid / NTBLK, bx = bid % NTBLK;
    const int t0 = bx * 16, t_max = t0 + 15;
    const int tid = threadIdx.x;
    const int tl = tid >> 4, j4 = (tid & 15) * 4;

    float4 acc = {0.f, 0.f, 0.f, 0.f};
    for (int scn = 0; scn < NSC; ++scn) {
        if (scn * FCH <= t_max) {
            const float4 v = *(const float4*)&opart[
                (((size_t)(b * NTBLK + bx)) * NSC + scn) * (TB * D_H) + tl * D_H + j4];
            acc.x += v.x; acc.y += v.y; acc.z += v.z; acc.w += v.w;
        }
    }
    *(float4*)&outp[((size_t)(b * T_TOT + t0 + tl)) * D_H + j4] = acc;
}

// ---------------------------------------------------------------------------
// Flash attention iter 1, s-split, online softmax, barrier-free.
// Grid (144, 8, 2); each wave owns 72 cols, writes its own {m,d,o} partial.
// ---------------------------------------------------------------------------
__global__ __launch_bounds__(256) void k_fattn1s(
    const u16* __restrict__ q_hi, const u16* __restrict__ k_hi,
    const u16* __restrict__ vT,
    float* __restrict__ fM, float* __restrict__ fD, float* __restrict__ fO)
{
    __shared__ u16 pstage[4][TB][40];

    const int b   = blockIdx.z;
    const int scn = blockIdx.y;
    const int bx  = blockIdx.x;
    const int t0 = bx * TB;
    const int t_max = t0 + TB - 1;
    if (scn * FCH > t_max) return;

    const int tid = threadIdx.x;
    const int wid = tid >> 6;
    const int lane = tid & 63;
    const int l15 = lane & 15, lg4 = lane >> 4;

    const size_t a_off = ((size_t)(b * T_TOT + t0 + l15)) * D_H + 8 * lg4;
    const short8 ah0 = *(const short8*)(q_hi + a_off);
    const short8 ah1 = *(const short8*)(q_hi + a_off + 32);
    const u16* kh = k_hi + (size_t)b * (T_TOT * D_H);

    const int w_lo  = scn * FCH + wid * (FCH / 4);     // 72-wide per wave
    const int w_end = min(w_lo + FCH / 4, t_max + 1);  // exclusive

    float m[4]   = {-3.0e38f, -3.0e38f, -3.0e38f, -3.0e38f};
    float den[4] = {0.f, 0.f, 0.f, 0.f};
    f32x4 oacc[4] = {};

    for (int s32 = w_lo; s32 < w_end; s32 += 32) {
        f32x4 acc0 = {0.f, 0.f, 0.f, 0.f};
        f32x4 acc1 = {0.f, 0.f, 0.f, 0.f};
        const bool ir1 = (s32 + 16) < w_end;
        {
            const size_t b_off = ((size_t)(s32 + l15)) * D_H + 8 * lg4;
            short8 b0 = *(const short8*)(kh + b_off);
            short8 b1 = *(const short8*)(kh + b_off + 32);
            acc0 = __builtin_amdgcn_mfma_f32_16x16x32_bf16(ah0, b0, acc0, 0, 0, 0);
            acc0 = __builtin_amdgcn_mfma_f32_16x16x32_bf16(ah1, b1, acc0, 0, 0, 0);
        }
        if (ir1) {
            const size_t b_off = ((size_t)(s32 + 16 + l15)) * D_H + 8 * lg4;
            short8 b0 = *(const short8*)(kh + b_off);
            short8 b1 = *(const short8*)(kh + b_off + 32);
            acc1 = __builtin_amdgcn_mfma_f32_16x16x32_bf16(ah0, b0, acc1, 0, 0, 0);
            acc1 = __builtin_amdgcn_mfma_f32_16x16x32_bf16(ah1, b1, acc1, 0, 0, 0);
        }
        #pragma unroll
        for (int r = 0; r < 4; ++r) {
            const int tl = 4 * lg4 + r;
            const int c0 = s32 + l15, c1 = s32 + 16 + l15;
            const bool v0 = (c0 < w_end) && (c0 <= t0 + tl);
            const bool v1 = ir1 && (c1 < w_end) && (c1 <= t0 + tl);
            const float sc0 = acc0[r] * SCALE;
            const float sc1 = acc1[r] * SCALE;
            float tmx = fmaxf(v0 ? sc0 : -3.0e38f, v1 ? sc1 : -3.0e38f);
            tmx = fmaxf(tmx, __shfl_xor(tmx, 1));
            tmx = fmaxf(tmx, __shfl_xor(tmx, 2));
            tmx = fmaxf(tmx, __shfl_xor(tmx, 4));
            tmx = fmaxf(tmx, __shfl_xor(tmx, 8));
            const float mn = fmaxf(m[r], tmx);
            const float scl = __expf(m[r] - mn);
            m[r] = mn;
            const float p0 = v0 ? __expf(sc0 - mn) : 0.f;
            const float p1 = v1 ? __expf(sc1 - mn) : 0.f;
            float ps = p0 + p1;
            ps += __shfl_xor(ps, 1); ps += __shfl_xor(ps, 2);
            ps += __shfl_xor(ps, 4); ps += __shfl_xor(ps, 8);
            den[r] = den[r] * scl + ps;
            #pragma unroll
            for (int j = 0; j < 4; ++j) oacc[j][r] *= scl;
            pstage[wid][tl][l15] = f2bf(p0);
            pstage[wid][tl][16 + l15] = f2bf(p1);
        }
        const short8 pa = *(const short8*)&pstage[wid][l15][8 * lg4];
        #pragma unroll
        for (int j = 0; j < 4; ++j) {
            const size_t v_off = ((size_t)(b * D_H + j * 16 + l15)) * T_TOT + s32 + 8 * lg4;
            short8 bv = *(const short8*)(vT + v_off);
            oacc[j] = __builtin_amdgcn_mfma_f32_16x16x32_bf16(pa, bv, oacc[j], 0, 0, 0);
        }
    }

    const size_t pidx = ((size_t)(b * NTBLK + bx)) * NPART + scn * 4 + wid;
    if (l15 == 0) {
        #pragma unroll
        for (int r = 0; r < 4; ++r) {
            fM[pidx * TB + 4 * lg4 + r] = m[r];
            fD[pidx * TB + 4 * lg4 + r] = den[r];
        }
    }
    #pragma unroll
    for (int j = 0; j < 4; ++j)
        #pragma unroll
        for (int r = 0; r < 4; ++r)
            fO[pidx * (TB * D_H) + (size_t)(4 * lg4 + r) * D_H + j * 16 + l15] = oacc[j][r];
}

__global__ __launch_bounds__(256) void k_fmerge(
    const float* __restrict__ fM, const float* __restrict__ fD,
    const float* __restrict__ fO, float* __restrict__ outp)
{
    const int bid = blockIdx.x;
    const int b = bid / NTBLK, bx = bid % NTBLK;
    const int t0 = bx * 16, t_max = t0 + 15;
    const int tid = threadIdx.x;
    const int tl = tid >> 4, j4 = (tid & 15) * 4;
    const size_t pb = (size_t)bid * NPART;

    float M = -3.0e38f;
    #pragma unroll
    for (int c = 0; c < NPART; ++c)
        if ((c >> 2) * FCH <= t_max) M = fmaxf(M, fM[(pb + c) * TB + tl]);

    float D = 0.f;
    float4 O = {0.f, 0.f, 0.f, 0.f};
    for (int c = 0; c < NPART; ++c) {
        if ((c >> 2) * FCH <= t_max) {
            const float w = __expf(fM[(pb + c) * TB + tl] - M);
            D += w * fD[(pb + c) * TB + tl];
            const float4 ov = *(const float4*)&fO[(pb + c) * (TB * D_H) + tl * D_H + j4];
            O.x += w * ov.x; O.y += w * ov.y; O.z += w * ov.z; O.w += w * ov.w;
        }
    }
    const float inv = 1.f / D;
    float4 res; res.x = O.x * inv; res.y = O.y * inv; res.z = O.z * inv; res.w = O.w * inv;
    *(float4*)&outp[((size_t)(b * T_TOT + t0 + tl)) * D_H + j4] = res;
}

// ---------------------------------------------------------------------------
extern "C" void kernel_launch(void* const* d_in, const int* in_sizes, int n_in,
                              void* d_out, int out_size, void* d_ws, size_t ws_size,
                              hipStream_t stream) {
    const float* x    = (const float*)d_in[0];
    const float* Wh   = (const float*)d_in[1];
    const float* Whs  = (const float*)d_in[2];
    const float* Whe  = (const float*)d_in[3];
    const float* Wk   = (const float*)d_in[4];
    const float* Wq   = (const float*)d_in[5];
    const float* Wv   = (const float*)d_in[6];
    const float* Wks  = (const float*)d_in[7];
    const float* Wqs  = (const float*)d_in[8];
    const float* Wvs  = (const float*)d_in[9];
    const float* Wke  = (const float*)d_in[10];
    const float* Wqe  = (const float*)d_in[11];
    const float* Wve  = (const float*)d_in[12];
    const float* ln_g  = (const float*)d_in[13];
    const float* ln_b  = (const float*)d_in[14];
    const float* ln_gs = (const float*)d_in[15];
    const float* ln_bs = (const float*)d_in[16];
    const float* ln_ge = (const float*)d_in[17];
    const float* ln_be = (const float*)d_in[18];
    const float* cope  = (const float*)d_in[19];

    float* out = (float*)d_out;

    const size_t N = (size_t)NROW * D_H;        // 294912
    char* W = (char*)d_ws;
    u16* xn_hi  = (u16*)W;    W += (size_t)NROW * D_IN * 2;
    u16* xn_lo  = (u16*)W;    W += (size_t)NROW * D_IN * 2;
    u16* wT_hi  = (u16*)W;    W += (size_t)3 * D_H * D_IN * 2;
    u16* wT_lo  = (u16*)W;    W += (size_t)3 * D_H * D_IN * 2;
    float* h    = (float*)W;  W += N * 4;
    u16* q_hi   = (u16*)W;    W += N * 2;
    u16* q_lo   = (u16*)W;    W += N * 2;
    u16* k_hi   = (u16*)W;    W += N * 2;
    u16* k_lo   = (u16*)W;    W += N * 2;
    u16* vT     = (u16*)W;    W += N * 2;
    u16* cT_hi  = (u16*)W;    W += (size_t)T_TOT * D_H * 2;
    u16* cT_lo  = (u16*)W;    W += (size_t)T_TOT * D_H * 2;
    float* logits = (float*)W; W += (size_t)BATCH * T_TOT * T_TOT * 4;
    float* lint   = (float*)W; W += (size_t)BATCH * T_TOT * T_TOT * 4;  // also p / h_part
    float* csum   = (float*)W; W += (size_t)NROW * NT16 * 4;
    float* totalv = (float*)W; W += (size_t)NROW * 4;
    float* mem1   = (float*)W; W += N * 4;
    float* opart  = (float*)W; W += (size_t)BATCH * NTBLK * NSC * TB * D_H * 4;
    float* fM     = (float*)W; W += (size_t)BATCH * NTBLK * NPART * TB * 4;
    float* fD     = (float*)W; W += (size_t)BATCH * NTBLK * NPART * TB * 4;
    float* fO     = (float*)W; W += (size_t)BATCH * NTBLK * NPART * TB * D_H * 4;

    float* h_part = lint;   // reused before lint is written (8 * N floats)

    k_ln<<<NROW, 256, 0, stream>>>(x, ln_g, ln_b, ln_gs, ln_bs, ln_ge, ln_be,
                                   xn_hi, xn_lo);
    k_prep<<<(WPREP_N + T_TOT * D_H + 255) / 256, 256, 0, stream>>>(
        Wh, Whs, Whe, cope, wT_hi, wT_lo, cT_hi, cT_lo);
    k_hgemm<<<dim3(NROW / 64, KCHUNKS), 256, 0, stream>>>(xn_hi, xn_lo, wT_hi, wT_lo, h_part);
    k_hred<<<(int)(N / 256), 256, 0, stream>>>(h_part, h);

    // iteration 0 (CoPE)
    k_qkv<true><<<NROW, 192, 0, stream>>>(h, Wk, Wq, Wv, Wks, Wqs, Wvs, Wke, Wqe, Wve,
                                          q_hi, q_lo, k_hi, k_lo, vT);
    k_score2c<<<dim3(T_TOT / 64, T_TOT / 64, BATCH), 256, 0, stream>>>(
        q_hi, q_lo, k_hi, k_lo, cT_hi, cT_lo, logits, lint, csum);
    k_csum<<<NROW / 4, 256, 0, stream>>>(csum, totalv);
    k_erow<<<NROW, 256, 0, stream>>>(logits, lint, totalv, lint);
    k_pv<<<dim3(NTBLK, NSC, BATCH), 256, 0, stream>>>(lint, vT, opart);
    k_pvmerge<<<BATCH * NTBLK, 256, 0, stream>>>(opart, mem1);

    // iteration 1 (plain causal, s-split online flash)
    k_qkv<false><<<NROW, 192, 0, stream>>>(mem1, Wk, Wq, Wv, Wks, Wqs, Wvs, Wke, Wqe, Wve,
                                           q_hi, q_lo, k_hi, k_lo, vT);
    k_fattn1s<<<dim3(NTBLK, NSC, BATCH), 256, 0, stream>>>(q_hi, k_hi, vT, fM, fD, fO);
    k_fmerge<<<BATCH * NTBLK, 256, 0, stream>>>(fM, fD, fO, out);
}

// Round 14
// 193.426 us; speedup vs baseline: 1.0163x; 1.0066x over previous
//
#include <hip/hip_runtime.h>

#define T_TOT 2304
#define S_LEN 128
#define D_IN  1024
#define D_H   64
#define BATCH 2
#define NROW  (BATCH * T_TOT)
#define CH    (T_TOT / 256)   // 9
#define SCALE 0.125f
#define KCHUNKS 8
#define KCW   (D_IN / KCHUNKS)   // 128
#define TB    16                 // t-rows per flash block
#define FCH   288                // s-chunk width (flash + pv split)
#define NSC   8                  // number of s-chunks
#define NTBLK (T_TOT / TB)       // 144
#define NT16  (T_TOT / 16)       // 144 col-tiles
#define NPART (NSC * 4)          // 32 partials per t-block

typedef unsigned short u16;
typedef __attribute__((ext_vector_type(8))) short short8;
typedef __attribute__((ext_vector_type(4))) float f32x4;
typedef __attribute__((ext_vector_type(4))) unsigned short u16x4;

static __device__ __forceinline__ u16 f2bf(float f) {
    unsigned u = __float_as_uint(f);
    unsigned r = (u + 0x7fffu + ((u >> 16) & 1u)) >> 16;
    return (u16)r;
}
static __device__ __forceinline__ float bf2f(u16 s) {
    return __uint_as_float((unsigned)s << 16);
}

// ---------------------------------------------------------------------------
// Kernel 1a: LayerNorm(x_row) -> xn hi/lo (split bf16). One block (256)/row.
// ---------------------------------------------------------------------------
__global__ __launch_bounds__(256) void k_ln(
    const float* __restrict__ x,
    const float* __restrict__ ln_g,  const float* __restrict__ ln_b,
    const float* __restrict__ ln_gs, const float* __restrict__ ln_bs,
    const float* __restrict__ ln_ge, const float* __restrict__ ln_be,
    u16* __restrict__ xn_hi, u16* __restrict__ xn_lo)
{
    __shared__ float red1[256], red2[256];
    const int row = blockIdx.x;
    const int t = row % T_TOT;
    const int tid = threadIdx.x;

    const float *gg, *bb;
    if (t < S_LEN)               { gg = ln_gs; bb = ln_bs; }
    else if (t >= T_TOT - S_LEN) { gg = ln_ge; bb = ln_be; }
    else                         { gg = ln_g;  bb = ln_b;  }

    const float4 xv = *(const float4*)(x + (size_t)row * D_IN + 4 * tid);
    float s  = xv.x + xv.y + xv.z + xv.w;
    float s2 = xv.x * xv.x + xv.y * xv.y + xv.z * xv.z + xv.w * xv.w;
    red1[tid] = s; red2[tid] = s2; __syncthreads();
    for (int off = 128; off > 0; off >>= 1) {
        if (tid < off) { red1[tid] += red1[tid + off]; red2[tid] += red2[tid + off]; }
        __syncthreads();
    }
    const float mean = red1[0] * (1.f / D_IN);
    const float var  = red2[0] * (1.f / D_IN) - mean * mean;
    const float rstd = rsqrtf(var + 1e-5f);

    const float4 gv = *(const float4*)(gg + 4 * tid);
    const float4 bv = *(const float4*)(bb + 4 * tid);
    float o0 = (xv.x - mean) * rstd * gv.x + bv.x;
    float o1 = (xv.y - mean) * rstd * gv.y + bv.y;
    float o2 = (xv.z - mean) * rstd * gv.z + bv.z;
    float o3 = (xv.w - mean) * rstd * gv.w + bv.w;

    u16x4 hv, lv;
    hv[0] = f2bf(o0); lv[0] = f2bf(o0 - bf2f(hv[0]));
    hv[1] = f2bf(o1); lv[1] = f2bf(o1 - bf2f(hv[1]));
    hv[2] = f2bf(o2); lv[2] = f2bf(o2 - bf2f(hv[2]));
    hv[3] = f2bf(o3); lv[3] = f2bf(o3 - bf2f(hv[3]));
    *(u16x4*)(xn_hi + (size_t)row * D_IN + 4 * tid) = hv;
    *(u16x4*)(xn_lo + (size_t)row * D_IN + 4 * tid) = lv;
}

// ---------------------------------------------------------------------------
// Kernel 1b: prep — transpose+split Wh/Whs/Whe, and split cope_emb^T
// ---------------------------------------------------------------------------
#define WPREP_N (3 * D_H * D_IN)
__global__ __launch_bounds__(256) void k_prep(
    const float* __restrict__ Wh, const float* __restrict__ Whs, const float* __restrict__ Whe,
    const float* __restrict__ cope,
    u16* __restrict__ wT_hi, u16* __restrict__ wT_lo,
    u16* __restrict__ cT_hi, u16* __restrict__ cT_lo)
{
    const int gid = blockIdx.x * 256 + threadIdx.x;
    if (gid < WPREP_N) {
        const int seg = gid >> 16;
        const int o = gid & 65535;
        const int j = o >> 10, k = o & 1023;
        const float* W = seg == 0 ? Wh : (seg == 1 ? Whs : Whe);
        const float f = W[k * D_H + j];
        const u16 hi = f2bf(f);
        wT_hi[gid] = hi;
        wT_lo[gid] = f2bf(f - bf2f(hi));
    } else {
        const int idx = gid - WPREP_N;
        if (idx < T_TOT * D_H) {
            const int n = idx >> 6, d = idx & 63;
            const float f = cope[(size_t)d * T_TOT + n];
            const u16 hi = f2bf(f);
            cT_hi[idx] = hi;
            cT_lo[idx] = f2bf(f - bf2f(hi));
        }
    }
}

// ---------------------------------------------------------------------------
// Kernel 1c: h_part[kc] = LN(x)[:, kc*128:+128] @ W_seg[kc chunk]  (MFMA, split)
// ---------------------------------------------------------------------------
__global__ __launch_bounds__(256) void k_hgemm(
    const u16* __restrict__ xn_hi, const u16* __restrict__ xn_lo,
    const u16* __restrict__ wT_hi, const u16* __restrict__ wT_lo,
    float* __restrict__ h_part)
{
    const int tile = blockIdx.x;              // 0..71
    const int kc   = blockIdx.y;              // 0..7
    const int k0   = kc * KCW;
    const int tt = tile % 36;
    const int seg = tt < 2 ? 1 : (tt >= 34 ? 2 : 0);

    __shared__ u16 Bh[64 * KCW];
    __shared__ u16 Bl[64 * KCW];

    const int tid = threadIdx.x;
    {
        const int r = tid >> 2;
        const int c0 = (tid & 3) * 32;
        const u16* sh = wT_hi + ((size_t)seg * D_H + r) * D_IN + k0 + c0;
        const u16* sl = wT_lo + ((size_t)seg * D_H + r) * D_IN + k0 + c0;
        const int sw = (r & 7) << 3;
        #pragma unroll
        for (int u = 0; u < 4; ++u) {
            const int col = c0 + 8 * u;
            *(short8*)&Bh[r * KCW + (col ^ sw)] = *(const short8*)(sh + 8 * u);
            *(short8*)&Bl[r * KCW + (col ^ sw)] = *(const short8*)(sl + 8 * u);
        }
    }
    __syncthreads();

    const int w = tid >> 6;
    const int lane = tid & 63;
    const int l15 = lane & 15, lg4 = lane >> 4;
    const int row0 = tile * 64 + w * 16;

    const size_t abase = (size_t)(row0 + l15) * D_IN + k0 + 8 * lg4;
    f32x4 acc[4] = {};

    #pragma unroll
    for (int kk = 0; kk < KCW / 32; ++kk) {
        short8 ah = *(const short8*)(xn_hi + abase + kk * 32);
        short8 al = *(const short8*)(xn_lo + abase + kk * 32);
        #pragma unroll
        for (int j = 0; j < 4; ++j) {
            const int brow = j * 16 + l15;
            const int col = (kk * 32 + 8 * lg4) ^ ((brow & 7) << 3);
            short8 bh = *(const short8*)&Bh[brow * KCW + col];
            short8 bl = *(const short8*)&Bl[brow * KCW + col];
            acc[j] = __builtin_amdgcn_mfma_f32_16x16x32_bf16(al, bh, acc[j], 0, 0, 0);
            acc[j] = __builtin_amdgcn_mfma_f32_16x16x32_bf16(ah, bl, acc[j], 0, 0, 0);
            acc[j] = __builtin_amdgcn_mfma_f32_16x16x32_bf16(ah, bh, acc[j], 0, 0, 0);
        }
    }
    float* hp = h_part + (size_t)kc * ((size_t)NROW * D_H);
    #pragma unroll
    for (int j = 0; j < 4; ++j)
        #pragma unroll
        for (int r = 0; r < 4; ++r)
            hp[(size_t)(row0 + 4 * lg4 + r) * D_H + j * 16 + l15] = acc[j][r];
}

// ---------------------------------------------------------------------------
// Kernel 1d: h = sum_kc h_part[kc]
// ---------------------------------------------------------------------------
__global__ __launch_bounds__(256) void k_hred(
    const float* __restrict__ h_part, float* __restrict__ h)
{
    const size_t idx = (size_t)blockIdx.x * 256 + threadIdx.x;
    const size_t N = (size_t)NROW * D_H;
    float s = 0.f;
    #pragma unroll
    for (int kc = 0; kc < KCHUNKS; ++kc) s += h_part[kc * N + idx];
    h[idx] = s;
}

// ---------------------------------------------------------------------------
// Kernel 2: q/k/v projections.
// ---------------------------------------------------------------------------
template <bool SPLIT>
__global__ __launch_bounds__(192) void k_qkv(
    const float* __restrict__ hin,
    const float* __restrict__ Wk,  const float* __restrict__ Wq,  const float* __restrict__ Wv,
    const float* __restrict__ Wks, const float* __restrict__ Wqs, const float* __restrict__ Wvs,
    const float* __restrict__ Wke, const float* __restrict__ Wqe, const float* __restrict__ Wve,
    u16* __restrict__ q_hi, u16* __restrict__ q_lo,
    u16* __restrict__ k_hi, u16* __restrict__ k_lo,
    u16* __restrict__ vT)
{
    __shared__ float hr[D_H];
    const int bid = blockIdx.x;
    const int b = bid / T_TOT, t = bid % T_TOT;
    const int tid = threadIdx.x;

    const float* hrow = hin + ((size_t)b * T_TOT + t) * D_H;
    if (tid < D_H) hr[tid] = hrow[tid];
    __syncthreads();

    const int which = tid >> 6, j = tid & 63;
    const float* W;
    if (t < S_LEN)               W = which == 0 ? Wks : (which == 1 ? Wqs : Wvs);
    else if (t >= T_TOT - S_LEN) W = which == 0 ? Wke : (which == 1 ? Wqe : Wve);
    else                         W = which == 0 ? Wk  : (which == 1 ? Wq  : Wv);

    float acc = 0.f;
    #pragma unroll
    for (int d = 0; d < D_H; ++d) acc += hr[d] * W[d * D_H + j];

    const size_t idx = ((size_t)b * T_TOT + t) * D_H + j;
    u16 hi = f2bf(acc);
    if (which == 0) {
        k_hi[idx] = hi;
        if (SPLIT) k_lo[idx] = f2bf(acc - bf2f(hi));
    } else if (which == 1) {
        q_hi[idx] = hi;
        if (SPLIT) q_lo[idx] = f2bf(acc - bf2f(hi));
    } else {
        vT[((size_t)b * D_H + j) * T_TOT + t] = hi;
    }
}

// ---------------------------------------------------------------------------
// k_gatesl (iter 0): dense QK^T (3-term split) -> per-16-tile sigmoid sums
// (csum) + CAUSAL-ONLY fp32 logits store. Grid (36, 36, 2); wave 16t x 64s.
// ---------------------------------------------------------------------------
__global__ __launch_bounds__(256) void k_gatesl(
    const u16* __restrict__ a_hi, const u16* __restrict__ a_lo,
    const u16* __restrict__ k_hi, const u16* __restrict__ k_lo,
    float* __restrict__ logits, float* __restrict__ csum)
{
    const int b  = blockIdx.z;
    const int s0 = blockIdx.x * 64;
    const int wid = threadIdx.x >> 6;
    const int t0 = blockIdx.y * 64 + wid * 16;
    const int wt_max = t0 + 15;
    const int lane = threadIdx.x & 63;
    const int l15 = lane & 15, lg4 = lane >> 4;

    const size_t a_off = ((size_t)(b * T_TOT + t0 + l15)) * D_H + 8 * lg4;
    const short8 ah0 = *(const short8*)(a_hi + a_off);
    const short8 ah1 = *(const short8*)(a_hi + a_off + 32);
    const short8 al0 = *(const short8*)(a_lo + a_off);
    const short8 al1 = *(const short8*)(a_lo + a_off + 32);

    const u16* bh = k_hi + (size_t)b * (T_TOT * D_H);
    const u16* bl = k_lo + (size_t)b * (T_TOT * D_H);
    float* o = logits + ((size_t)(b * T_TOT + t0 + 4 * lg4)) * T_TOT + s0 + l15;

    #pragma unroll
    for (int ni = 0; ni < 4; ++ni) {
        const size_t b_off = ((size_t)(s0 + ni * 16 + l15)) * D_H + 8 * lg4;
        short8 bh0 = *(const short8*)(bh + b_off);
        short8 bh1 = *(const short8*)(bh + b_off + 32);
        short8 bl0 = *(const short8*)(bl + b_off);
        short8 bl1 = *(const short8*)(bl + b_off + 32);
        f32x4 acc = {0.f, 0.f, 0.f, 0.f};
        acc = __builtin_amdgcn_mfma_f32_16x16x32_bf16(al0, bh0, acc, 0, 0, 0);
        acc = __builtin_amdgcn_mfma_f32_16x16x32_bf16(al1, bh1, acc, 0, 0, 0);
        acc = __builtin_amdgcn_mfma_f32_16x16x32_bf16(ah0, bl0, acc, 0, 0, 0);
        acc = __builtin_amdgcn_mfma_f32_16x16x32_bf16(ah1, bl1, acc, 0, 0, 0);
        acc = __builtin_amdgcn_mfma_f32_16x16x32_bf16(ah0, bh0, acc, 0, 0, 0);
        acc = __builtin_amdgcn_mfma_f32_16x16x32_bf16(ah1, bh1, acc, 0, 0, 0);
        const int c16 = (s0 >> 4) + ni;
        #pragma unroll
        for (int r = 0; r < 4; ++r) {
            float g = 1.f / (1.f + __expf(-acc[r]));
            g += __shfl_xor(g, 1); g += __shfl_xor(g, 2);
            g += __shfl_xor(g, 4); g += __shfl_xor(g, 8);
            if (l15 == 0)
                csum[((size_t)(b * T_TOT + t0 + 4 * lg4 + r)) * NT16 + c16] = g;
        }
        if (s0 + ni * 16 <= wt_max) {
            #pragma unroll
            for (int r = 0; r < 4; ++r)
                o[(size_t)r * T_TOT + ni * 16] = acc[r];
        }
    }
}

// ---------------------------------------------------------------------------
// k_csum: totalv[row] = sum of csum tiles. One wave per row, coalesced.
// ---------------------------------------------------------------------------
__global__ __launch_bounds__(256) void k_csum(
    const float* __restrict__ csum, float* __restrict__ totalv)
{
    const int row = blockIdx.x * 4 + (threadIdx.x >> 6);
    const int lane = threadIdx.x & 63;
    const size_t base = (size_t)row * NT16;
    float v = csum[base + lane] + csum[base + 64 + lane];
    if (128 + lane < NT16) v += csum[base + 128 + lane];
    #pragma unroll
    for (int off = 32; off > 0; off >>= 1) v += __shfl_xor(v, off);
    if (lane == 0) totalv[row] = v;
}

// ---------------------------------------------------------------------------
// k_lintb (iter 0): lint = q.cope (3-term split), BOUNDED: per-wave skip of
// s-tiles beyond max(floor(tot)+2) over the wave's 16 rows (erow never
// gathers past its row's Lc <= that bound). Grid (36, 36, 2).
// ---------------------------------------------------------------------------
__global__ __launch_bounds__(256) void k_lintb(
    const u16* __restrict__ a_hi, const u16* __restrict__ a_lo,
    const u16* __restrict__ c_hi, const u16* __restrict__ c_lo,
    const float* __restrict__ totalv,
    float* __restrict__ lint)
{
    const int b  = blockIdx.z;
    const int s0 = blockIdx.x * 64;
    const int wid = threadIdx.x >> 6;
    const int t0 = blockIdx.y * 64 + wid * 16;
    const int lane = threadIdx.x & 63;
    const int l15 = lane & 15, lg4 = lane >> 4;

    // per-wave column bound from the 16 rows' dense gate totals
    float tv = totalv[b * T_TOT + t0 + l15];
    tv = fmaxf(tv, __shfl_xor(tv, 1));
    tv = fmaxf(tv, __shfl_xor(tv, 2));
    tv = fmaxf(tv, __shfl_xor(tv, 4));
    tv = fmaxf(tv, __shfl_xor(tv, 8));
    const int bound = min((int)tv + 2, T_TOT);
    if (s0 >= bound) return;

    const size_t a_off = ((size_t)(b * T_TOT + t0 + l15)) * D_H + 8 * lg4;
    const short8 ah0 = *(const short8*)(a_hi + a_off);
    const short8 ah1 = *(const short8*)(a_hi + a_off + 32);
    const short8 al0 = *(const short8*)(a_lo + a_off);
    const short8 al1 = *(const short8*)(a_lo + a_off + 32);

    float* o = lint + ((size_t)(b * T_TOT + t0 + 4 * lg4)) * T_TOT + s0 + l15;

    #pragma unroll
    for (int ni = 0; ni < 4; ++ni) {
        const size_t b_off = ((size_t)(s0 + ni * 16 + l15)) * D_H + 8 * lg4;
        short8 bh0 = *(const short8*)(c_hi + b_off);
        short8 bh1 = *(const short8*)(c_hi + b_off + 32);
        short8 bl0 = *(const short8*)(c_lo + b_off);
        short8 bl1 = *(const short8*)(c_lo + b_off + 32);
        f32x4 acc = {0.f, 0.f, 0.f, 0.f};
        acc = __builtin_amdgcn_mfma_f32_16x16x32_bf16(al0, bh0, acc, 0, 0, 0);
        acc = __builtin_amdgcn_mfma_f32_16x16x32_bf16(al1, bh1, acc, 0, 0, 0);
        acc = __builtin_amdgcn_mfma_f32_16x16x32_bf16(ah0, bl0, acc, 0, 0, 0);
        acc = __builtin_amdgcn_mfma_f32_16x16x32_bf16(ah1, bl1, acc, 0, 0, 0);
        acc = __builtin_amdgcn_mfma_f32_16x16x32_bf16(ah0, bh0, acc, 0, 0, 0);
        acc = __builtin_amdgcn_mfma_f32_16x16x32_bf16(ah1, bh1, acc, 0, 0, 0);
        #pragma unroll
        for (int r = 0; r < 4; ++r)
            o[(size_t)r * T_TOT + ni * 16] = acc[r];
    }
}

// ---------------------------------------------------------------------------
// Row kernel (iter 0): CoPE scan + bias + softmax, causal-only traffic.
// ---------------------------------------------------------------------------
__global__ __launch_bounds__(256) void k_erow(
    const float* __restrict__ logits,
    const float* __restrict__ lint,
    const float* __restrict__ totalv,
    float* __restrict__ pbase)
{
    __shared__ float lg[T_TOT];
    __shared__ float extra[2 * T_TOT];
    __shared__ float wtot[4], wmax[4], wsum[4];

    const int row = blockIdx.x;
    const int t = row % T_TOT;
    const int Lt16 = (t | 15) + 1;                // causal, 16-aligned
    const int Lw = min((Lt16 + 31) & ~31, T_TOT); // 32-aligned write bound (k_pv tail)
    const int tid = threadIdx.x;
    const int lane = tid & 63, wid = tid >> 6;
    const float* lrow = logits + (size_t)row * T_TOT;
    const float tot = totalv[row];
    const int Lc = min((int)tot + 2, T_TOT);      // lint columns ever gathered

    for (int s = tid; s < Lt16; s += 256) lg[s] = lrow[s];
    {
        const float* lintrow = lint + (size_t)row * T_TOT;
        for (int s = tid; s < Lc; s += 256) extra[T_TOT + s] = lintrow[s];
    }
    __syncthreads();

    // gates (causal only; masked g=0) + block-wide exclusive prefix
    {
        const int base = tid * CH;
        float gv[CH];
        float lsum = 0.f;
        #pragma unroll
        for (int u = 0; u < CH; ++u) {
            const int s = base + u;
            float g = (s <= t) ? 1.f / (1.f + expf(-lg[s])) : 0.f;
            gv[u] = g;
            lsum += g;
        }
        float cs = lsum;
        #pragma unroll
        for (int off = 1; off < 64; off <<= 1) {
            float n = __shfl_up(cs, off);
            if (lane >= off) cs += n;
        }
        if (lane == 63) wtot[wid] = cs;
        __syncthreads();
        float pre = 0.f;
        #pragma unroll
        for (int w = 0; w < 4; ++w) {
            float vv = wtot[w];
            if (w < wid) pre += vv;
        }
        float run = pre + cs - lsum;
        #pragma unroll
        for (int u = 0; u < CH; ++u) {
            const int s = base + u;
            if (s <= t) {
                float p = fminf(fmaxf(tot - run, 0.f), (float)(T_TOT - 1));
                extra[s] = p;
            }
            run += gv[u];
        }
        __syncthreads();
    }

    float scv[CH];
    float mx = -3.4e38f;
    #pragma unroll
    for (int r = 0; r < CH; ++r) {
        int sidx = tid + 256 * r;
        float sc = -3.4e38f;
        if (sidx <= t) {
            sc = lg[sidx] * SCALE;
            float p = extra[sidx];
            float pf = floorf(p);
            int fi = (int)pf;
            int ci = (int)ceilf(p);
            float w = p - pf;
            sc += extra[T_TOT + ci] * w + extra[T_TOT + fi] * (1.f - w);
            mx = fmaxf(mx, sc);
        }
        scv[r] = sc;
    }
    #pragma unroll
    for (int off = 32; off > 0; off >>= 1) mx = fmaxf(mx, __shfl_xor(mx, off));
    if (lane == 0) wmax[wid] = mx;
    __syncthreads();
    mx = fmaxf(fmaxf(wmax[0], wmax[1]), fmaxf(wmax[2], wmax[3]));

    float pvv[CH];
    float psum = 0.f;
    #pragma unroll
    for (int r = 0; r < CH; ++r) {
        int sidx = tid + 256 * r;
        float pv = 0.f;
        if (sidx <= t) { pv = expf(scv[r] - mx); psum += pv; }
        pvv[r] = pv;
    }
    #pragma unroll
    for (int off = 32; off > 0; off >>= 1) psum += __shfl_xor(psum, off);
    if (lane == 0) wsum[wid] = psum;
    __syncthreads();
    const float inv = 1.f / (wsum[0] + wsum[1] + wsum[2] + wsum[3]);

    u16* prow = (u16*)(pbase + (size_t)row * T_TOT);
    #pragma unroll
    for (int r = 0; r < CH; ++r) {
        int sidx = tid + 256 * r;
        if (sidx < Lw) prow[sidx] = f2bf(pvv[r] * inv);   // zeros beyond t
    }
}

// ---------------------------------------------------------------------------
// PV GEMM, s-split (iter 0): partial O over an s-chunk; merged by k_pvmerge.
// ---------------------------------------------------------------------------
__global__ __launch_bounds__(256) void k_pv(
    const float* __restrict__ pbuf, const u16* __restrict__ vT,
    float* __restrict__ opart)
{
    const int b  = blockIdx.z;
    const int scn = blockIdx.y;
    const int bx = blockIdx.x;
    const int t0 = bx * 16;
    const int sstart = scn * FCH;
    const int send = min(sstart + FCH, t0 + 16);
    if (sstart >= send) return;

    const int j0 = (threadIdx.x >> 6) * 16;
    const int lane = threadIdx.x & 63;
    const int l15 = lane & 15, lg4 = lane >> 4;

    const u16* pb = (const u16*)pbuf
        + ((size_t)(b * T_TOT + t0 + l15)) * (2 * (size_t)T_TOT) + 8 * lg4;
    const u16* vb = vT + ((size_t)(b * D_H + j0 + l15)) * T_TOT + 8 * lg4;

    f32x4 a0 = {}, a1 = {}, a2 = {}, a3 = {};
    int s = sstart;
    for (; s + 128 <= send; s += 128) {
        short8 p0 = *(const short8*)(pb + s);
        short8 v0 = *(const short8*)(vb + s);
        short8 p1 = *(const short8*)(pb + s + 32);
        short8 v1 = *(const short8*)(vb + s + 32);
        short8 p2 = *(const short8*)(pb + s + 64);
        short8 v2 = *(const short8*)(vb + s + 64);
        short8 p3 = *(const short8*)(pb + s + 96);
        short8 v3 = *(const short8*)(vb + s + 96);
        a0 = __builtin_amdgcn_mfma_f32_16x16x32_bf16(p0, v0, a0, 0, 0, 0);
        a1 = __builtin_amdgcn_mfma_f32_16x16x32_bf16(p1, v1, a1, 0, 0, 0);
        a2 = __builtin_amdgcn_mfma_f32_16x16x32_bf16(p2, v2, a2, 0, 0, 0);
        a3 = __builtin_amdgcn_mfma_f32_16x16x32_bf16(p3, v3, a3, 0, 0, 0);
    }
    for (; s < send; s += 32) {
        short8 p0 = *(const short8*)(pb + s);
        short8 v0 = *(const short8*)(vb + s);
        a0 = __builtin_amdgcn_mfma_f32_16x16x32_bf16(p0, v0, a0, 0, 0, 0);
    }
    f32x4 acc = (a0 + a1) + (a2 + a3);
    float* ob = opart + (((size_t)(b * NTBLK + bx)) * NSC + scn) * (TB * D_H)
              + (size_t)(4 * lg4) * D_H + j0 + l15;
    #pragma unroll
    for (int r = 0; r < 4; ++r) ob[(size_t)r * D_H] = acc[r];
}

__global__ __launch_bounds__(256) void k_pvmerge(
    const float* __restrict__ opart, float* __restrict__ outp)
{
    const int bid = blockIdx.x;
    const int b = bid / NTBLK, bx = bid % NTBLK;
    const int t0 = bx * 16, t_max = t0 + 15;
    const int tid = threadIdx.x;
    const int tl = tid >> 4, j4 = (tid & 15) * 4;

    float4 acc = {0.f, 0.f, 0.f, 0.f};
    for (int scn = 0; scn < NSC; ++scn) {
        if (scn * FCH <= t_max) {
            const float4 v = *(const float4*)&opart[
                (((size_t)(b * NTBLK + bx)) * NSC + scn) * (TB * D_H) + tl * D_H + j4];
            acc.x += v.x; acc.y += v.y; acc.z += v.z; acc.w += v.w;
        }
    }
    *(float4*)&outp[((size_t)(b * T_TOT + t0 + tl)) * D_H + j4] = acc;
}

// ---------------------------------------------------------------------------
// Flash attention iter 1, s-split, online softmax, barrier-free.
// ---------------------------------------------------------------------------
__global__ __launch_bounds__(256) void k_fattn1s(
    const u16* __restrict__ q_hi, const u16* __restrict__ k_hi,
    const u16* __restrict__ vT,
    float* __restrict__ fM, float* __restrict__ fD, float* __restrict__ fO)
{
    __shared__ u16 pstage[4][TB][40];

    const int b   = blockIdx.z;
    const int scn = blockIdx.y;
    const int bx  = blockIdx.x;
    const int t0 = bx * TB;
    const int t_max = t0 + TB - 1;
    if (scn * FCH > t_max) return;

    const int tid = threadIdx.x;
    const int wid = tid >> 6;
    const int lane = tid & 63;
    const int l15 = lane & 15, lg4 = lane >> 4;

    const size_t a_off = ((size_t)(b * T_TOT + t0 + l15)) * D_H + 8 * lg4;
    const short8 ah0 = *(const short8*)(q_hi + a_off);
    const short8 ah1 = *(const short8*)(q_hi + a_off + 32);
    const u16* kh = k_hi + (size_t)b * (T_TOT * D_H);

    const int w_lo  = scn * FCH + wid * (FCH / 4);     // 72-wide per wave
    const int w_end = min(w_lo + FCH / 4, t_max + 1);  // exclusive

    float m[4]   = {-3.0e38f, -3.0e38f, -3.0e38f, -3.0e38f};
    float den[4] = {0.f, 0.f, 0.f, 0.f};
    f32x4 oacc[4] = {};

    for (int s32 = w_lo; s32 < w_end; s32 += 32) {
        f32x4 acc0 = {0.f, 0.f, 0.f, 0.f};
        f32x4 acc1 = {0.f, 0.f, 0.f, 0.f};
        const bool ir1 = (s32 + 16) < w_end;
        {
            const size_t b_off = ((size_t)(s32 + l15)) * D_H + 8 * lg4;
            short8 b0 = *(const short8*)(kh + b_off);
            short8 b1 = *(const short8*)(kh + b_off + 32);
            acc0 = __builtin_amdgcn_mfma_f32_16x16x32_bf16(ah0, b0, acc0, 0, 0, 0);
            acc0 = __builtin_amdgcn_mfma_f32_16x16x32_bf16(ah1, b1, acc0, 0, 0, 0);
        }
        if (ir1) {
            const size_t b_off = ((size_t)(s32 + 16 + l15)) * D_H + 8 * lg4;
            short8 b0 = *(const short8*)(kh + b_off);
            short8 b1 = *(const short8*)(kh + b_off + 32);
            acc1 = __builtin_amdgcn_mfma_f32_16x16x32_bf16(ah0, b0, acc1, 0, 0, 0);
            acc1 = __builtin_amdgcn_mfma_f32_16x16x32_bf16(ah1, b1, acc1, 0, 0, 0);
        }
        #pragma unroll
        for (int r = 0; r < 4; ++r) {
            const int tl = 4 * lg4 + r;
            const int c0 = s32 + l15, c1 = s32 + 16 + l15;
            const bool v0 = (c0 < w_end) && (c0 <= t0 + tl);
            const bool v1 = ir1 && (c1 < w_end) && (c1 <= t0 + tl);
            const float sc0 = acc0[r] * SCALE;
            const float sc1 = acc1[r] * SCALE;
            float tmx = fmaxf(v0 ? sc0 : -3.0e38f, v1 ? sc1 : -3.0e38f);
            tmx = fmaxf(tmx, __shfl_xor(tmx, 1));
            tmx = fmaxf(tmx, __shfl_xor(tmx, 2));
            tmx = fmaxf(tmx, __shfl_xor(tmx, 4));
            tmx = fmaxf(tmx, __shfl_xor(tmx, 8));
            const float mn = fmaxf(m[r], tmx);
            const float scl = __expf(m[r] - mn);
            m[r] = mn;
            const float p0 = v0 ? __expf(sc0 - mn) : 0.f;
            const float p1 = v1 ? __expf(sc1 - mn) : 0.f;
            float ps = p0 + p1;
            ps += __shfl_xor(ps, 1); ps += __shfl_xor(ps, 2);
            ps += __shfl_xor(ps, 4); ps += __shfl_xor(ps, 8);
            den[r] = den[r] * scl + ps;
            #pragma unroll
            for (int j = 0; j < 4; ++j) oacc[j][r] *= scl;
            pstage[wid][tl][l15] = f2bf(p0);
            pstage[wid][tl][16 + l15] = f2bf(p1);
        }
        const short8 pa = *(const short8*)&pstage[wid][l15][8 * lg4];
        #pragma unroll
        for (int j = 0; j < 4; ++j) {
            const size_t v_off = ((size_t)(b * D_H + j * 16 + l15)) * T_TOT + s32 + 8 * lg4;
            short8 bv = *(const short8*)(vT + v_off);
            oacc[j] = __builtin_amdgcn_mfma_f32_16x16x32_bf16(pa, bv, oacc[j], 0, 0, 0);
        }
    }

    const size_t pidx = ((size_t)(b * NTBLK + bx)) * NPART + scn * 4 + wid;
    if (l15 == 0) {
        #pragma unroll
        for (int r = 0; r < 4; ++r) {
            fM[pidx * TB + 4 * lg4 + r] = m[r];
            fD[pidx * TB + 4 * lg4 + r] = den[r];
        }
    }
    #pragma unroll
    for (int j = 0; j < 4; ++j)
        #pragma unroll
        for (int r = 0; r < 4; ++r)
            fO[pidx * (TB * D_H) + (size_t)(4 * lg4 + r) * D_H + j * 16 + l15] = oacc[j][r];
}

__global__ __launch_bounds__(256) void k_fmerge(
    const float* __restrict__ fM, const float* __restrict__ fD,
    const float* __restrict__ fO, float* __restrict__ outp)
{
    const int bid = blockIdx.x;
    const int b = bid / NTBLK, bx = bid % NTBLK;
    const int t0 = bx * 16, t_max = t0 + 15;
    const int tid = threadIdx.x;
    const int tl = tid >> 4, j4 = (tid & 15) * 4;
    const size_t pb = (size_t)bid * NPART;

    float M = -3.0e38f;
    #pragma unroll
    for (int c = 0; c < NPART; ++c)
        if ((c >> 2) * FCH <= t_max) M = fmaxf(M, fM[(pb + c) * TB + tl]);

    float D = 0.f;
    float4 O = {0.f, 0.f, 0.f, 0.f};
    for (int c = 0; c < NPART; ++c) {
        if ((c >> 2) * FCH <= t_max) {
            const float w = __expf(fM[(pb + c) * TB + tl] - M);
            D += w * fD[(pb + c) * TB + tl];
            const float4 ov = *(const float4*)&fO[(pb + c) * (TB * D_H) + tl * D_H + j4];
            O.x += w * ov.x; O.y += w * ov.y; O.z += w * ov.z; O.w += w * ov.w;
        }
    }
    const float inv = 1.f / D;
    float4 res; res.x = O.x * inv; res.y = O.y * inv; res.z = O.z * inv; res.w = O.w * inv;
    *(float4*)&outp[((size_t)(b * T_TOT + t0 + tl)) * D_H + j4] = res;
}

// ---------------------------------------------------------------------------
extern "C" void kernel_launch(void* const* d_in, const int* in_sizes, int n_in,
                              void* d_out, int out_size, void* d_ws, size_t ws_size,
                              hipStream_t stream) {
    const float* x    = (const float*)d_in[0];
    const float* Wh   = (const float*)d_in[1];
    const float* Whs  = (const float*)d_in[2];
    const float* Whe  = (const float*)d_in[3];
    const float* Wk   = (const float*)d_in[4];
    const float* Wq   = (const float*)d_in[5];
    const float* Wv   = (const float*)d_in[6];
    const float* Wks  = (const float*)d_in[7];
    const float* Wqs  = (const float*)d_in[8];
    const float* Wvs  = (const float*)d_in[9];
    const float* Wke  = (const float*)d_in[10];
    const float* Wqe  = (const float*)d_in[11];
    const float* Wve  = (const float*)d_in[12];
    const float* ln_g  = (const float*)d_in[13];
    const float* ln_b  = (const float*)d_in[14];
    const float* ln_gs = (const float*)d_in[15];
    const float* ln_bs = (const float*)d_in[16];
    const float* ln_ge = (const float*)d_in[17];
    const float* ln_be = (const float*)d_in[18];
    const float* cope  = (const float*)d_in[19];

    float* out = (float*)d_out;

    const size_t N = (size_t)NROW * D_H;        // 294912
    char* W = (char*)d_ws;
    u16* xn_hi  = (u16*)W;    W += (size_t)NROW * D_IN * 2;
    u16* xn_lo  = (u16*)W;    W += (size_t)NROW * D_IN * 2;
    u16* wT_hi  = (u16*)W;    W += (size_t)3 * D_H * D_IN * 2;
    u16* wT_lo  = (u16*)W;    W += (size_t)3 * D_H * D_IN * 2;
    float* h    = (float*)W;  W += N * 4;
    u16* q_hi   = (u16*)W;    W += N * 2;
    u16* q_lo   = (u16*)W;    W += N * 2;
    u16* k_hi   = (u16*)W;    W += N * 2;
    u16* k_lo   = (u16*)W;    W += N * 2;
    u16* vT     = (u16*)W;    W += N * 2;
    u16* cT_hi  = (u16*)W;    W += (size_t)T_TOT * D_H * 2;
    u16* cT_lo  = (u16*)W;    W += (size_t)T_TOT * D_H * 2;
    float* logits = (float*)W; W += (size_t)BATCH * T_TOT * T_TOT * 4;
    float* lint   = (float*)W; W += (size_t)BATCH * T_TOT * T_TOT * 4;  // also p / h_part
    float* csum   = (float*)W; W += (size_t)NROW * NT16 * 4;
    float* totalv = (float*)W; W += (size_t)NROW * 4;
    float* mem1   = (float*)W; W += N * 4;
    float* opart  = (float*)W; W += (size_t)BATCH * NTBLK * NSC * TB * D_H * 4;
    float* fM     = (float*)W; W += (size_t)BATCH * NTBLK * NPART * TB * 4;
    float* fD     = (float*)W; W += (size_t)BATCH * NTBLK * NPART * TB * 4;
    float* fO     = (float*)W; W += (size_t)BATCH * NTBLK * NPART * TB * D_H * 4;

    float* h_part = lint;   // reused before lint is written (8 * N floats)

    k_ln<<<NROW, 256, 0, stream>>>(x, ln_g, ln_b, ln_gs, ln_bs, ln_ge, ln_be,
                                   xn_hi, xn_lo);
    k_prep<<<(WPREP_N + T_TOT * D_H + 255) / 256, 256, 0, stream>>>(
        Wh, Whs, Whe, cope, wT_hi, wT_lo, cT_hi, cT_lo);
    k_hgemm<<<dim3(NROW / 64, KCHUNKS), 256, 0, stream>>>(xn_hi, xn_lo, wT_hi, wT_lo, h_part);
    k_hred<<<(int)(N / 256), 256, 0, stream>>>(h_part, h);

    // iteration 0 (CoPE)
    k_qkv<true><<<NROW, 192, 0, stream>>>(h, Wk, Wq, Wv, Wks, Wqs, Wvs, Wke, Wqe, Wve,
                                          q_hi, q_lo, k_hi, k_lo, vT);
    k_gatesl<<<dim3(T_TOT / 64, T_TOT / 64, BATCH), 256, 0, stream>>>(
        q_hi, q_lo, k_hi, k_lo, logits, csum);
    k_csum<<<NROW / 4, 256, 0, stream>>>(csum, totalv);
    k_lintb<<<dim3(T_TOT / 64, T_TOT / 64, BATCH), 256, 0, stream>>>(
        q_hi, q_lo, cT_hi, cT_lo, totalv, lint);
    k_erow<<<NROW, 256, 0, stream>>>(logits, lint, totalv, lint);
    k_pv<<<dim3(NTBLK, NSC, BATCH), 256, 0, stream>>>(lint, vT, opart);
    k_pvmerge<<<BATCH * NTBLK, 256, 0, stream>>>(opart, mem1);

    // iteration 1 (plain causal, s-split online flash)
    k_qkv<false><<<NROW, 192, 0, stream>>>(mem1, Wk, Wq, Wv, Wks, Wqs, Wvs, Wke, Wqe, Wve,
                                           q_hi, q_lo, k_hi, k_lo, vT);
    k_fattn1s<<<dim3(NTBLK, NSC, BATCH), 256, 0, stream>>>(q_hi, k_hi, vT, fM, fD, fO);
    k_fmerge<<<BATCH * NTBLK, 256, 0, stream>>>(fM, fD, fO, out);
}

// Round 15
// 180.173 us; speedup vs baseline: 1.0910x; 1.0736x over previous
//
#include <hip/hip_runtime.h>

#define T_TOT 2304
#define S_LEN 128
#define D_IN  1024
#define D_H   64
#define BATCH 2
#define NROW  (BATCH * T_TOT)
#define CH    (T_TOT / 256)   // 9
#define SCALE 0.125f
#define KCHUNKS 8
#define KCW   (D_IN / KCHUNKS)   // 128
#define TB    16                 // t-rows per flash block
#define FCH   288                // s-chunk width (flash + pv split)
#define NSC   8                  // number of s-chunks
#define NTBLK (T_TOT / TB)       // 144
#define NPART (NSC * 4)          // 32 partials per t-block

typedef unsigned short u16;
typedef __attribute__((ext_vector_type(8))) short short8;
typedef __attribute__((ext_vector_type(4))) float f32x4;
typedef __attribute__((ext_vector_type(4))) unsigned short u16x4;

static __device__ __forceinline__ u16 f2bf(float f) {
    unsigned u = __float_as_uint(f);
    unsigned r = (u + 0x7fffu + ((u >> 16) & 1u)) >> 16;
    return (u16)r;
}
static __device__ __forceinline__ float bf2f(u16 s) {
    return __uint_as_float((unsigned)s << 16);
}

// ---------------------------------------------------------------------------
// Kernel 1a: LayerNorm(x_row) -> xn hi/lo (split bf16). One block (256)/row.
// ---------------------------------------------------------------------------
__global__ __launch_bounds__(256) void k_ln(
    const float* __restrict__ x,
    const float* __restrict__ ln_g,  const float* __restrict__ ln_b,
    const float* __restrict__ ln_gs, const float* __restrict__ ln_bs,
    const float* __restrict__ ln_ge, const float* __restrict__ ln_be,
    u16* __restrict__ xn_hi, u16* __restrict__ xn_lo)
{
    __shared__ float red1[256], red2[256];
    const int row = blockIdx.x;
    const int t = row % T_TOT;
    const int tid = threadIdx.x;

    const float *gg, *bb;
    if (t < S_LEN)               { gg = ln_gs; bb = ln_bs; }
    else if (t >= T_TOT - S_LEN) { gg = ln_ge; bb = ln_be; }
    else                         { gg = ln_g;  bb = ln_b;  }

    const float4 xv = *(const float4*)(x + (size_t)row * D_IN + 4 * tid);
    float s  = xv.x + xv.y + xv.z + xv.w;
    float s2 = xv.x * xv.x + xv.y * xv.y + xv.z * xv.z + xv.w * xv.w;
    red1[tid] = s; red2[tid] = s2; __syncthreads();
    for (int off = 128; off > 0; off >>= 1) {
        if (tid < off) { red1[tid] += red1[tid + off]; red2[tid] += red2[tid + off]; }
        __syncthreads();
    }
    const float mean = red1[0] * (1.f / D_IN);
    const float var  = red2[0] * (1.f / D_IN) - mean * mean;
    const float rstd = rsqrtf(var + 1e-5f);

    const float4 gv = *(const float4*)(gg + 4 * tid);
    const float4 bv = *(const float4*)(bb + 4 * tid);
    float o0 = (xv.x - mean) * rstd * gv.x + bv.x;
    float o1 = (xv.y - mean) * rstd * gv.y + bv.y;
    float o2 = (xv.z - mean) * rstd * gv.z + bv.z;
    float o3 = (xv.w - mean) * rstd * gv.w + bv.w;

    u16x4 hv, lv;
    hv[0] = f2bf(o0); lv[0] = f2bf(o0 - bf2f(hv[0]));
    hv[1] = f2bf(o1); lv[1] = f2bf(o1 - bf2f(hv[1]));
    hv[2] = f2bf(o2); lv[2] = f2bf(o2 - bf2f(hv[2]));
    hv[3] = f2bf(o3); lv[3] = f2bf(o3 - bf2f(hv[3]));
    *(u16x4*)(xn_hi + (size_t)row * D_IN + 4 * tid) = hv;
    *(u16x4*)(xn_lo + (size_t)row * D_IN + 4 * tid) = lv;
}

// ---------------------------------------------------------------------------
// Kernel 1b: prep — transpose+split Wh/Whs/Whe, and split cope_emb^T
// ---------------------------------------------------------------------------
#define WPREP_N (3 * D_H * D_IN)
__global__ __launch_bounds__(256) void k_prep(
    const float* __restrict__ Wh, const float* __restrict__ Whs, const float* __restrict__ Whe,
    const float* __restrict__ cope,
    u16* __restrict__ wT_hi, u16* __restrict__ wT_lo,
    u16* __restrict__ cT_hi, u16* __restrict__ cT_lo)
{
    const int gid = blockIdx.x * 256 + threadIdx.x;
    if (gid < WPREP_N) {
        const int seg = gid >> 16;
        const int o = gid & 65535;
        const int j = o >> 10, k = o & 1023;
        const float* W = seg == 0 ? Wh : (seg == 1 ? Whs : Whe);
        const float f = W[k * D_H + j];
        const u16 hi = f2bf(f);
        wT_hi[gid] = hi;
        wT_lo[gid] = f2bf(f - bf2f(hi));
    } else {
        const int idx = gid - WPREP_N;
        if (idx < T_TOT * D_H) {
            const int n = idx >> 6, d = idx & 63;
            const float f = cope[(size_t)d * T_TOT + n];
            const u16 hi = f2bf(f);
            cT_hi[idx] = hi;
            cT_lo[idx] = f2bf(f - bf2f(hi));
        }
    }
}

// ---------------------------------------------------------------------------
// Kernel 1c: h_part[kc] = LN(x)[:, kc*128:+128] @ W_seg[kc chunk]  (MFMA, split)
// ---------------------------------------------------------------------------
__global__ __launch_bounds__(256) void k_hgemm(
    const u16* __restrict__ xn_hi, const u16* __restrict__ xn_lo,
    const u16* __restrict__ wT_hi, const u16* __restrict__ wT_lo,
    float* __restrict__ h_part)
{
    const int tile = blockIdx.x;              // 0..71
    const int kc   = blockIdx.y;              // 0..7
    const int k0   = kc * KCW;
    const int tt = tile % 36;
    const int seg = tt < 2 ? 1 : (tt >= 34 ? 2 : 0);

    __shared__ u16 Bh[64 * KCW];
    __shared__ u16 Bl[64 * KCW];

    const int tid = threadIdx.x;
    {
        const int r = tid >> 2;
        const int c0 = (tid & 3) * 32;
        const u16* sh = wT_hi + ((size_t)seg * D_H + r) * D_IN + k0 + c0;
        const u16* sl = wT_lo + ((size_t)seg * D_H + r) * D_IN + k0 + c0;
        const int sw = (r & 7) << 3;
        #pragma unroll
        for (int u = 0; u < 4; ++u) {
            const int col = c0 + 8 * u;
            *(short8*)&Bh[r * KCW + (col ^ sw)] = *(const short8*)(sh + 8 * u);
            *(short8*)&Bl[r * KCW + (col ^ sw)] = *(const short8*)(sl + 8 * u);
        }
    }
    __syncthreads();

    const int w = tid >> 6;
    const int lane = tid & 63;
    const int l15 = lane & 15, lg4 = lane >> 4;
    const int row0 = tile * 64 + w * 16;

    const size_t abase = (size_t)(row0 + l15) * D_IN + k0 + 8 * lg4;
    f32x4 acc[4] = {};

    #pragma unroll
    for (int kk = 0; kk < KCW / 32; ++kk) {
        short8 ah = *(const short8*)(xn_hi + abase + kk * 32);
        short8 al = *(const short8*)(xn_lo + abase + kk * 32);
        #pragma unroll
        for (int j = 0; j < 4; ++j) {
            const int brow = j * 16 + l15;
            const int col = (kk * 32 + 8 * lg4) ^ ((brow & 7) << 3);
            short8 bh = *(const short8*)&Bh[brow * KCW + col];
            short8 bl = *(const short8*)&Bl[brow * KCW + col];
            acc[j] = __builtin_amdgcn_mfma_f32_16x16x32_bf16(al, bh, acc[j], 0, 0, 0);
            acc[j] = __builtin_amdgcn_mfma_f32_16x16x32_bf16(ah, bl, acc[j], 0, 0, 0);
            acc[j] = __builtin_amdgcn_mfma_f32_16x16x32_bf16(ah, bh, acc[j], 0, 0, 0);
        }
    }
    float* hp = h_part + (size_t)kc * ((size_t)NROW * D_H);
    #pragma unroll
    for (int j = 0; j < 4; ++j)
        #pragma unroll
        for (int r = 0; r < 4; ++r)
            hp[(size_t)(row0 + 4 * lg4 + r) * D_H + j * 16 + l15] = acc[j][r];
}

// ---------------------------------------------------------------------------
// Kernel 1d: h = sum_kc h_part[kc]
// ---------------------------------------------------------------------------
__global__ __launch_bounds__(256) void k_hred(
    const float* __restrict__ h_part, float* __restrict__ h)
{
    const size_t idx = (size_t)blockIdx.x * 256 + threadIdx.x;
    const size_t N = (size_t)NROW * D_H;
    float s = 0.f;
    #pragma unroll
    for (int kc = 0; kc < KCHUNKS; ++kc) s += h_part[kc * N + idx];
    h[idx] = s;
}

// ---------------------------------------------------------------------------
// Kernel 2: q/k/v projections.
// ---------------------------------------------------------------------------
template <bool SPLIT>
__global__ __launch_bounds__(192) void k_qkv(
    const float* __restrict__ hin,
    const float* __restrict__ Wk,  const float* __restrict__ Wq,  const float* __restrict__ Wv,
    const float* __restrict__ Wks, const float* __restrict__ Wqs, const float* __restrict__ Wvs,
    const float* __restrict__ Wke, const float* __restrict__ Wqe, const float* __restrict__ Wve,
    u16* __restrict__ q_hi, u16* __restrict__ q_lo,
    u16* __restrict__ k_hi, u16* __restrict__ k_lo,
    u16* __restrict__ vT)
{
    __shared__ float hr[D_H];
    const int bid = blockIdx.x;
    const int b = bid / T_TOT, t = bid % T_TOT;
    const int tid = threadIdx.x;

    const float* hrow = hin + ((size_t)b * T_TOT + t) * D_H;
    if (tid < D_H) hr[tid] = hrow[tid];
    __syncthreads();

    const int which = tid >> 6, j = tid & 63;
    const float* W;
    if (t < S_LEN)               W = which == 0 ? Wks : (which == 1 ? Wqs : Wvs);
    else if (t >= T_TOT - S_LEN) W = which == 0 ? Wke : (which == 1 ? Wqe : Wve);
    else                         W = which == 0 ? Wk  : (which == 1 ? Wq  : Wv);

    float acc = 0.f;
    #pragma unroll
    for (int d = 0; d < D_H; ++d) acc += hr[d] * W[d * D_H + j];

    const size_t idx = ((size_t)b * T_TOT + t) * D_H + j;
    u16 hi = f2bf(acc);
    if (which == 0) {
        k_hi[idx] = hi;
        if (SPLIT) k_lo[idx] = f2bf(acc - bf2f(hi));
    } else if (which == 1) {
        q_hi[idx] = hi;
        if (SPLIT) q_lo[idx] = f2bf(acc - bf2f(hi));
    } else {
        vT[((size_t)b * D_H + j) * T_TOT + t] = hi;
    }
}

// ---------------------------------------------------------------------------
// Fused dual score GEMM (iter 0): logits = q.k^T and lint = q.cope, 3-term
// split. Fine grid (36 s-tiles x 36 t-tiles x 2) for occupancy.
// ---------------------------------------------------------------------------
__global__ __launch_bounds__(256) void k_score2(
    const u16* __restrict__ a_hi, const u16* __restrict__ a_lo,
    const u16* __restrict__ k_hi, const u16* __restrict__ k_lo,
    const u16* __restrict__ c_hi, const u16* __restrict__ c_lo,
    float* __restrict__ logits, float* __restrict__ lint)
{
    const int b  = blockIdx.z;
    const int s0 = blockIdx.x * 64;
    const int wid = threadIdx.x >> 6;
    const int t0 = blockIdx.y * 64 + wid * 16;
    const int lane = threadIdx.x & 63;
    const int l15 = lane & 15, lg4 = lane >> 4;

    const size_t a_off = ((size_t)(b * T_TOT + t0 + l15)) * D_H + 8 * lg4;
    const short8 ah0 = *(const short8*)(a_hi + a_off);
    const short8 ah1 = *(const short8*)(a_hi + a_off + 32);
    const short8 al0 = *(const short8*)(a_lo + a_off);
    const short8 al1 = *(const short8*)(a_lo + a_off + 32);

    const size_t orow_off = ((size_t)(b * T_TOT + t0 + 4 * lg4)) * T_TOT + s0 + l15;

    const u16* bh = k_hi + (size_t)b * (T_TOT * D_H);
    const u16* bl = k_lo + (size_t)b * (T_TOT * D_H);
    float* o = logits + orow_off;

    #pragma unroll
    for (int pass = 0; pass < 2; ++pass) {
        #pragma unroll
        for (int ni = 0; ni < 4; ++ni) {
            const size_t b_off = ((size_t)(s0 + ni * 16 + l15)) * D_H + 8 * lg4;
            short8 bh0 = *(const short8*)(bh + b_off);
            short8 bh1 = *(const short8*)(bh + b_off + 32);
            short8 bl0 = *(const short8*)(bl + b_off);
            short8 bl1 = *(const short8*)(bl + b_off + 32);
            f32x4 acc = {0.f, 0.f, 0.f, 0.f};
            acc = __builtin_amdgcn_mfma_f32_16x16x32_bf16(al0, bh0, acc, 0, 0, 0);
            acc = __builtin_amdgcn_mfma_f32_16x16x32_bf16(al1, bh1, acc, 0, 0, 0);
            acc = __builtin_amdgcn_mfma_f32_16x16x32_bf16(ah0, bl0, acc, 0, 0, 0);
            acc = __builtin_amdgcn_mfma_f32_16x16x32_bf16(ah1, bl1, acc, 0, 0, 0);
            acc = __builtin_amdgcn_mfma_f32_16x16x32_bf16(ah0, bh0, acc, 0, 0, 0);
            acc = __builtin_amdgcn_mfma_f32_16x16x32_bf16(ah1, bh1, acc, 0, 0, 0);
            #pragma unroll
            for (int r = 0; r < 4; ++r)
                o[(size_t)r * T_TOT + ni * 16] = acc[r];
        }
        bh = c_hi; bl = c_lo;      // cope has no batch stride
        o = lint + orow_off;
    }
}

// ---------------------------------------------------------------------------
// Row kernel (iter 0): CoPE scan + bias + softmax. Writes p (bf16) to pbase.
// ---------------------------------------------------------------------------
__global__ __launch_bounds__(256) void k_erow(
    const float* __restrict__ logits,
    const float* __restrict__ lint,
    float* __restrict__ pbase)
{
    __shared__ float lg[T_TOT];
    __shared__ float extra[2 * T_TOT];
    __shared__ float wtot[4], wmax[4], wsum[4];

    const int row = blockIdx.x;
    const int t = row % T_TOT;
    const int tid = threadIdx.x;
    const int lane = tid & 63, wid = tid >> 6;
    const float* lrow = logits + (size_t)row * T_TOT;

    for (int r = 0; r < CH; ++r) { int s = tid + 256 * r; lg[s] = lrow[s]; }
    __syncthreads();

    {
        const int base = tid * CH;
        float gv[CH];
        float lsum = 0.f;
        #pragma unroll
        for (int u = 0; u < CH; ++u) {
            float g = 1.f / (1.f + expf(-lg[base + u]));
            gv[u] = g;
            lsum += g;
        }
        float cs = lsum;
        #pragma unroll
        for (int off = 1; off < 64; off <<= 1) {
            float n = __shfl_up(cs, off);
            if (lane >= off) cs += n;
        }
        if (lane == 63) wtot[wid] = cs;
        __syncthreads();
        float pre = 0.f, tot = 0.f;
        #pragma unroll
        for (int w = 0; w < 4; ++w) {
            float vv = wtot[w];
            tot += vv;
            if (w < wid) pre += vv;
        }
        float run = pre + cs - lsum;
        #pragma unroll
        for (int u = 0; u < CH; ++u) {
            float p = fminf(tot - run, (float)(T_TOT - 1));
            extra[base + u] = p;
            run += gv[u];
        }
        const float* lintrow = lint + (size_t)row * T_TOT;
        for (int r = 0; r < CH; ++r) { int s = tid + 256 * r; extra[T_TOT + s] = lintrow[s]; }
        __syncthreads();
    }

    float scv[CH];
    float mx = -3.4e38f;
    #pragma unroll
    for (int r = 0; r < CH; ++r) {
        int sidx = tid + 256 * r;
        float sc = -3.4e38f;
        if (sidx <= t) {
            sc = lg[sidx] * SCALE;
            float p = extra[sidx];
            float pf = floorf(p);
            int fi = (int)pf;
            int ci = (int)ceilf(p);
            float w = p - pf;
            sc += extra[T_TOT + ci] * w + extra[T_TOT + fi] * (1.f - w);
            mx = fmaxf(mx, sc);
        }
        scv[r] = sc;
    }
    #pragma unroll
    for (int off = 32; off > 0; off >>= 1) mx = fmaxf(mx, __shfl_xor(mx, off));
    if (lane == 0) wmax[wid] = mx;
    __syncthreads();
    mx = fmaxf(fmaxf(wmax[0], wmax[1]), fmaxf(wmax[2], wmax[3]));

    float pvv[CH];
    float psum = 0.f;
    #pragma unroll
    for (int r = 0; r < CH; ++r) {
        int sidx = tid + 256 * r;
        float pv = 0.f;
        if (sidx <= t) { pv = expf(scv[r] - mx); psum += pv; }
        pvv[r] = pv;
    }
    #pragma unroll
    for (int off = 32; off > 0; off >>= 1) psum += __shfl_xor(psum, off);
    if (lane == 0) wsum[wid] = psum;
    __syncthreads();
    const float inv = 1.f / (wsum[0] + wsum[1] + wsum[2] + wsum[3]);

    u16* prow = (u16*)(pbase + (size_t)row * T_TOT);
    #pragma unroll
    for (int r = 0; r < CH; ++r) {
        int sidx = tid + 256 * r;
        prow[sidx] = f2bf(pvv[r] * inv);
    }
}

// ---------------------------------------------------------------------------
// PV GEMM, s-split (iter 0): partial O over an s-chunk; merged by k_pvmerge.
// ---------------------------------------------------------------------------
__global__ __launch_bounds__(256) void k_pv(
    const float* __restrict__ pbuf, const u16* __restrict__ vT,
    float* __restrict__ opart)
{
    const int b  = blockIdx.z;
    const int scn = blockIdx.y;
    const int bx = blockIdx.x;
    const int t0 = bx * 16;
    const int sstart = scn * FCH;
    const int send = min(sstart + FCH, t0 + 16);
    if (sstart >= send) return;

    const int j0 = (threadIdx.x >> 6) * 16;
    const int lane = threadIdx.x & 63;
    const int l15 = lane & 15, lg4 = lane >> 4;

    const u16* pb = (const u16*)pbuf
        + ((size_t)(b * T_TOT + t0 + l15)) * (2 * (size_t)T_TOT) + 8 * lg4;
    const u16* vb = vT + ((size_t)(b * D_H + j0 + l15)) * T_TOT + 8 * lg4;

    f32x4 a0 = {}, a1 = {}, a2 = {}, a3 = {};
    int s = sstart;
    for (; s + 128 <= send; s += 128) {
        short8 p0 = *(const short8*)(pb + s);
        short8 v0 = *(const short8*)(vb + s);
        short8 p1 = *(const short8*)(pb + s + 32);
        short8 v1 = *(const short8*)(vb + s + 32);
        short8 p2 = *(const short8*)(pb + s + 64);
        short8 v2 = *(const short8*)(vb + s + 64);
        short8 p3 = *(const short8*)(pb + s + 96);
        short8 v3 = *(const short8*)(vb + s + 96);
        a0 = __builtin_amdgcn_mfma_f32_16x16x32_bf16(p0, v0, a0, 0, 0, 0);
        a1 = __builtin_amdgcn_mfma_f32_16x16x32_bf16(p1, v1, a1, 0, 0, 0);
        a2 = __builtin_amdgcn_mfma_f32_16x16x32_bf16(p2, v2, a2, 0, 0, 0);
        a3 = __builtin_amdgcn_mfma_f32_16x16x32_bf16(p3, v3, a3, 0, 0, 0);
    }
    for (; s < send; s += 32) {
        short8 p0 = *(const short8*)(pb + s);
        short8 v0 = *(const short8*)(vb + s);
        a0 = __builtin_amdgcn_mfma_f32_16x16x32_bf16(p0, v0, a0, 0, 0, 0);
    }
    f32x4 acc = (a0 + a1) + (a2 + a3);
    float* ob = opart + (((size_t)(b * NTBLK + bx)) * NSC + scn) * (TB * D_H)
              + (size_t)(4 * lg4) * D_H + j0 + l15;
    #pragma unroll
    for (int r = 0; r < 4; ++r) ob[(size_t)r * D_H] = acc[r];
}

__global__ __launch_bounds__(256) void k_pvmerge(
    const float* __restrict__ opart, float* __restrict__ outp)
{
    const int bid = blockIdx.x;
    const int b = bid / NTBLK, bx = bid % NTBLK;
    const int t0 = bx * 16, t_max = t0 + 15;
    const int tid = threadIdx.x;
    const int tl = tid >> 4, j4 = (tid & 15) * 4;

    float4 acc = {0.f, 0.f, 0.f, 0.f};
    for (int scn = 0; scn < NSC; ++scn) {
        if (scn * FCH <= t_max) {
            const float4 v = *(const float4*)&opart[
                (((size_t)(b * NTBLK + bx)) * NSC + scn) * (TB * D_H) + tl * D_H + j4];
            acc.x += v.x; acc.y += v.y; acc.z += v.z; acc.w += v.w;
        }
    }
    *(float4*)&outp[((size_t)(b * T_TOT + t0 + tl)) * D_H + j4] = acc;
}

// ---------------------------------------------------------------------------
// Flash attention iter 1, s-split, online softmax, barrier-free.
// Grid (144, 8, 2); each wave owns 72 cols, writes its own {m,d,o} partial.
// ---------------------------------------------------------------------------
__global__ __launch_bounds__(256) void k_fattn1s(
    const u16* __restrict__ q_hi, const u16* __restrict__ k_hi,
    const u16* __restrict__ vT,
    float* __restrict__ fM, float* __restrict__ fD, float* __restrict__ fO)
{
    __shared__ u16 pstage[4][TB][32];

    const int b   = blockIdx.z;
    const int scn = blockIdx.y;
    const int bx  = blockIdx.x;
    const int t0 = bx * TB;
    const int t_max = t0 + TB - 1;
    if (scn * FCH > t_max) return;

    const int tid = threadIdx.x;
    const int wid = tid >> 6;
    const int lane = tid & 63;
    const int l15 = lane & 15, lg4 = lane >> 4;

    const size_t a_off = ((size_t)(b * T_TOT + t0 + l15)) * D_H + 8 * lg4;
    const short8 ah0 = *(const short8*)(q_hi + a_off);
    const short8 ah1 = *(const short8*)(q_hi + a_off + 32);
    const u16* kh = k_hi + (size_t)b * (T_TOT * D_H);

    const int w_lo  = scn * FCH + wid * (FCH / 4);     // 72-wide per wave
    const int w_end = min(w_lo + FCH / 4, t_max + 1);  // exclusive

    float m[4]   = {-3.0e38f, -3.0e38f, -3.0e38f, -3.0e38f};
    float den[4] = {0.f, 0.f, 0.f, 0.f};
    f32x4 oacc[4] = {};

    for (int s32 = w_lo; s32 < w_end; s32 += 32) {
        f32x4 acc0 = {0.f, 0.f, 0.f, 0.f};
        f32x4 acc1 = {0.f, 0.f, 0.f, 0.f};
        const bool ir1 = (s32 + 16) < w_end;
        {
            const size_t b_off = ((size_t)(s32 + l15)) * D_H + 8 * lg4;
            short8 b0 = *(const short8*)(kh + b_off);
            short8 b1 = *(const short8*)(kh + b_off + 32);
            acc0 = __builtin_amdgcn_mfma_f32_16x16x32_bf16(ah0, b0, acc0, 0, 0, 0);
            acc0 = __builtin_amdgcn_mfma_f32_16x16x32_bf16(ah1, b1, acc0, 0, 0, 0);
        }
        if (ir1) {
            const size_t b_off = ((size_t)(s32 + 16 + l15)) * D_H + 8 * lg4;
            short8 b0 = *(const short8*)(kh + b_off);
            short8 b1 = *(const short8*)(kh + b_off + 32);
            acc1 = __builtin_amdgcn_mfma_f32_16x16x32_bf16(ah0, b0, acc1, 0, 0, 0);
            acc1 = __builtin_amdgcn_mfma_f32_16x16x32_bf16(ah1, b1, acc1, 0, 0, 0);
        }
        #pragma unroll
        for (int r = 0; r < 4; ++r) {
            const int tl = 4 * lg4 + r;
            const int c0 = s32 + l15, c1 = s32 + 16 + l15;
            const bool v0 = (c0 < w_end) && (c0 <= t0 + tl);
            const bool v1 = ir1 && (c1 < w_end) && (c1 <= t0 + tl);
            const float sc0 = acc0[r] * SCALE;
            const float sc1 = acc1[r] * SCALE;
            float tmx = fmaxf(v0 ? sc0 : -3.0e38f, v1 ? sc1 : -3.0e38f);
            tmx = fmaxf(tmx, __shfl_xor(tmx, 1));
            tmx = fmaxf(tmx, __shfl_xor(tmx, 2));
            tmx = fmaxf(tmx, __shfl_xor(tmx, 4));
            tmx = fmaxf(tmx, __shfl_xor(tmx, 8));
            const float mn = fmaxf(m[r], tmx);
            const float scl = __expf(m[r] - mn);
            m[r] = mn;
            const float p0 = v0 ? __expf(sc0 - mn) : 0.f;
            const float p1 = v1 ? __expf(sc1 - mn) : 0.f;
            float ps = p0 + p1;
            ps += __shfl_xor(ps, 1); ps += __shfl_xor(ps, 2);
            ps += __shfl_xor(ps, 4); ps += __shfl_xor(ps, 8);
            den[r] = den[r] * scl + ps;
            #pragma unroll
            for (int j = 0; j < 4; ++j) oacc[j][r] *= scl;
            pstage[wid][tl][l15] = f2bf(p0);
            pstage[wid][tl][16 + l15] = f2bf(p1);
        }
        const short8 pa = *(const short8*)&pstage[wid][l15][8 * lg4];
        #pragma unroll
        for (int j = 0; j < 4; ++j) {
            const size_t v_off = ((size_t)(b * D_H + j * 16 + l15)) * T_TOT + s32 + 8 * lg4;
            short8 bv = *(const short8*)(vT + v_off);
            oacc[j] = __builtin_amdgcn_mfma_f32_16x16x32_bf16(pa, bv, oacc[j], 0, 0, 0);
        }
    }

    const size_t pidx = ((size_t)(b * NTBLK + bx)) * NPART + scn * 4 + wid;
    if (l15 == 0) {
        #pragma unroll
        for (int r = 0; r < 4; ++r) {
            fM[pidx * TB + 4 * lg4 + r] = m[r];
            fD[pidx * TB + 4 * lg4 + r] = den[r];
        }
    }
    #pragma unroll
    for (int j = 0; j < 4; ++j)
        #pragma unroll
        for (int r = 0; r < 4; ++r)
            fO[pidx * (TB * D_H) + (size_t)(4 * lg4 + r) * D_H + j * 16 + l15] = oacc[j][r];
}

__global__ __launch_bounds__(256) void k_fmerge(
    const float* __restrict__ fM, const float* __restrict__ fD,
    const float* __restrict__ fO, float* __restrict__ outp)
{
    const int bid = blockIdx.x;
    const int b = bid / NTBLK, bx = bid % NTBLK;
    const int t0 = bx * 16, t_max = t0 + 15;
    const int tid = threadIdx.x;
    const int tl = tid >> 4, j4 = (tid & 15) * 4;
    const size_t pb = (size_t)bid * NPART;

    float M = -3.0e38f;
    #pragma unroll
    for (int c = 0; c < NPART; ++c)
        if ((c >> 2) * FCH <= t_max) M = fmaxf(M, fM[(pb + c) * TB + tl]);

    float D = 0.f;
    float4 O = {0.f, 0.f, 0.f, 0.f};
    for (int c = 0; c < NPART; ++c) {
        if ((c >> 2) * FCH <= t_max) {
            const float w = __expf(fM[(pb + c) * TB + tl] - M);
            D += w * fD[(pb + c) * TB + tl];
            const float4 ov = *(const float4*)&fO[(pb + c) * (TB * D_H) + tl * D_H + j4];
            O.x += w * ov.x; O.y += w * ov.y; O.z += w * ov.z; O.w += w * ov.w;
        }
    }
    const float inv = 1.f / D;
    float4 res; res.x = O.x * inv; res.y = O.y * inv; res.z = O.z * inv; res.w = O.w * inv;
    *(float4*)&outp[((size_t)(b * T_TOT + t0 + tl)) * D_H + j4] = res;
}

// ---------------------------------------------------------------------------
extern "C" void kernel_launch(void* const* d_in, const int* in_sizes, int n_in,
                              void* d_out, int out_size, void* d_ws, size_t ws_size,
                              hipStream_t stream) {
    const float* x    = (const float*)d_in[0];
    const float* Wh   = (const float*)d_in[1];
    const float* Whs  = (const float*)d_in[2];
    const float* Whe  = (const float*)d_in[3];
    const float* Wk   = (const float*)d_in[4];
    const float* Wq   = (const float*)d_in[5];
    const float* Wv   = (const float*)d_in[6];
    const float* Wks  = (const float*)d_in[7];
    const float* Wqs  = (const float*)d_in[8];
    const float* Wvs  = (const float*)d_in[9];
    const float* Wke  = (const float*)d_in[10];
    const float* Wqe  = (const float*)d_in[11];
    const float* Wve  = (const float*)d_in[12];
    const float* ln_g  = (const float*)d_in[13];
    const float* ln_b  = (const float*)d_in[14];
    const float* ln_gs = (const float*)d_in[15];
    const float* ln_bs = (const float*)d_in[16];
    const float* ln_ge = (const float*)d_in[17];
    const float* ln_be = (const float*)d_in[18];
    const float* cope  = (const float*)d_in[19];

    float* out = (float*)d_out;

    const size_t N = (size_t)NROW * D_H;        // 294912
    char* W = (char*)d_ws;
    u16* xn_hi  = (u16*)W;    W += (size_t)NROW * D_IN * 2;
    u16* xn_lo  = (u16*)W;    W += (size_t)NROW * D_IN * 2;
    u16* wT_hi  = (u16*)W;    W += (size_t)3 * D_H * D_IN * 2;
    u16* wT_lo  = (u16*)W;    W += (size_t)3 * D_H * D_IN * 2;
    float* h    = (float*)W;  W += N * 4;
    u16* q_hi   = (u16*)W;    W += N * 2;
    u16* q_lo   = (u16*)W;    W += N * 2;
    u16* k_hi   = (u16*)W;    W += N * 2;
    u16* k_lo   = (u16*)W;    W += N * 2;
    u16* vT     = (u16*)W;    W += N * 2;
    u16* cT_hi  = (u16*)W;    W += (size_t)T_TOT * D_H * 2;
    u16* cT_lo  = (u16*)W;    W += (size_t)T_TOT * D_H * 2;
    float* logits = (float*)W; W += (size_t)BATCH * T_TOT * T_TOT * 4;
    float* lint   = (float*)W; W += (size_t)BATCH * T_TOT * T_TOT * 4;  // also p / h_part
    float* mem1   = (float*)W; W += N * 4;
    float* opart  = (float*)W; W += (size_t)BATCH * NTBLK * NSC * TB * D_H * 4;
    float* fM     = (float*)W; W += (size_t)BATCH * NTBLK * NPART * TB * 4;
    float* fD     = (float*)W; W += (size_t)BATCH * NTBLK * NPART * TB * 4;
    float* fO     = (float*)W; W += (size_t)BATCH * NTBLK * NPART * TB * D_H * 4;

    float* h_part = lint;   // reused before lint is written (8 * N floats)

    k_ln<<<NROW, 256, 0, stream>>>(x, ln_g, ln_b, ln_gs, ln_bs, ln_ge, ln_be,
                                   xn_hi, xn_lo);
    k_prep<<<(WPREP_N + T_TOT * D_H + 255) / 256, 256, 0, stream>>>(
        Wh, Whs, Whe, cope, wT_hi, wT_lo, cT_hi, cT_lo);
    k_hgemm<<<dim3(NROW / 64, KCHUNKS), 256, 0, stream>>>(xn_hi, xn_lo, wT_hi, wT_lo, h_part);
    k_hred<<<(int)(N / 256), 256, 0, stream>>>(h_part, h);

    // iteration 0 (CoPE)
    k_qkv<true><<<NROW, 192, 0, stream>>>(h, Wk, Wq, Wv, Wks, Wqs, Wvs, Wke, Wqe, Wve,
                                          q_hi, q_lo, k_hi, k_lo, vT);
    k_score2<<<dim3(T_TOT / 64, T_TOT / 64, BATCH), 256, 0, stream>>>(
        q_hi, q_lo, k_hi, k_lo, cT_hi, cT_lo, logits, lint);
    k_erow<<<NROW, 256, 0, stream>>>(logits, lint, lint);
    k_pv<<<dim3(NTBLK, NSC, BATCH), 256, 0, stream>>>(lint, vT, opart);
    k_pvmerge<<<BATCH * NTBLK, 256, 0, stream>>>(opart, mem1);

    // iteration 1 (plain causal, s-split online flash)
    k_qkv<false><<<NROW, 192, 0, stream>>>(mem1, Wk, Wq, Wv, Wks, Wqs, Wvs, Wke, Wqe, Wve,
                                           q_hi, q_lo, k_hi, k_lo, vT);
    k_fattn1s<<<dim3(NTBLK, NSC, BATCH), 256, 0, stream>>>(q_hi, k_hi, vT, fM, fD, fO);
    k_fmerge<<<BATCH * NTBLK, 256, 0, stream>>>(fM, fD, fO, out);
}